// Round 1
// 405.422 us; speedup vs baseline: 1.0756x; 1.0756x over previous
//
#include <hip/hip_runtime.h>
#include <hip/hip_bf16.h>
#include <math.h>

typedef __bf16 bf16;
typedef __bf16 bf16x2 __attribute__((ext_vector_type(2)));
typedef __bf16 bf16x8 __attribute__((ext_vector_type(8)));
typedef float f32x4 __attribute__((ext_vector_type(4)));
typedef float f32x16 __attribute__((ext_vector_type(16)));
typedef unsigned int u32;
typedef unsigned int u32x2 __attribute__((ext_vector_type(2)));
typedef unsigned int u32x4 __attribute__((ext_vector_type(4)));

#define SCALE 0.125f
#define L2E 1.4426950408889634f

// async global->LDS, 16B per lane. LDS dest must be wave-uniform base + lane*16.
#define GLOAD_LDS16(gptr, lptr)                                      \
  __builtin_amdgcn_global_load_lds(                                  \
      (const __attribute__((address_space(1))) void*)(gptr),         \
      (__attribute__((address_space(3))) void*)(lptr), 16, 0, 0)

// pack two f32 -> one u32 of 2 bf16 (RNE); compiler emits v_cvt_pk_bf16_f32
__device__ __forceinline__ u32 pk_bf16(float lo, float hi) {
  bf16x2 t;
  t[0] = (bf16)lo;
  t[1] = (bf16)hi;
  return __builtin_bit_cast(u32, t);
}

// v_permlane32_swap_b32: a.hi <-> b.lo  (a becomes {a.lo, b.lo_old}, b becomes {a.hi_old, b.hi})
__device__ __forceinline__ void plane32_swap(u32& a, u32& b) {
  asm volatile("v_permlane32_swap_b32 %0, %1" : "+v"(a), "+v"(b));
}

// ---------------- row LayerNorm: fp32 in -> bf16 out, one block per row of 1024 ----------------
__global__ __launch_bounds__(256) void ln_f32(const float* __restrict__ x,
                                              const float* __restrict__ g,
                                              const float* __restrict__ b,
                                              bf16* __restrict__ y) {
  long base = (long)blockIdx.x * 1024;
  int tid = threadIdx.x;
  float v[4];
#pragma unroll
  for (int i = 0; i < 4; i++) v[i] = x[base + tid + i * 256];
  float s1 = v[0] + v[1] + v[2] + v[3];
  float s2 = v[0] * v[0] + v[1] * v[1] + v[2] * v[2] + v[3] * v[3];
#pragma unroll
  for (int off = 32; off; off >>= 1) {
    s1 += __shfl_xor(s1, off);
    s2 += __shfl_xor(s2, off);
  }
  __shared__ float aux[2][4];
  int wave = tid >> 6, lane = tid & 63;
  if (lane == 0) { aux[0][wave] = s1; aux[1][wave] = s2; }
  __syncthreads();
  float S1 = aux[0][0] + aux[0][1] + aux[0][2] + aux[0][3];
  float S2 = aux[1][0] + aux[1][1] + aux[1][2] + aux[1][3];
  float mean = S1 * (1.0f / 1024.0f);
  float var = S2 * (1.0f / 1024.0f) - mean * mean;
  float rs = rsqrtf(var + 1e-5f);
#pragma unroll
  for (int i = 0; i < 4; i++) {
    int c = tid + i * 256;
    y[base + c] = (bf16)(((v[i] - mean) * rs) * g[c] + b[c]);
  }
}

// ---------------- W[K][N] fp32 -> Wt[N][K] bf16 tiled transpose ----------------
__global__ __launch_bounds__(256) void transpose_w(const float* __restrict__ W,
                                                   bf16* __restrict__ Wt,
                                                   int K, int N) {
  __shared__ bf16 tile[64][66];
  int n0 = blockIdx.x * 64, k0 = blockIdx.y * 64;
  int c = threadIdx.x & 63, r4 = threadIdx.x >> 6;
#pragma unroll
  for (int i = 0; i < 16; i++)
    tile[i * 4 + r4][c] = (bf16)W[(long)(k0 + i * 4 + r4) * N + n0 + c];
  __syncthreads();
#pragma unroll
  for (int i = 0; i < 16; i++)
    Wt[(long)(n0 + i * 4 + r4) * K + k0 + c] = tile[c][i * 4 + r4];
}

// ------- extract V^T per (b,h): Vt[bh][d][n] = KV[b*1024+n][1024 + h*64 + d] (bf16) -------
__global__ __launch_bounds__(256) void extract_vt(const bf16* __restrict__ KV,
                                                  bf16* __restrict__ Vt) {
  __shared__ bf16 tile[64][66];
  int bh = blockIdx.z, b = bh >> 4, h = bh & 15;
  const bf16* src = KV + (long)b * 1024 * 2048 + 1024 + h * 64;
  bf16* dst = Vt + (long)bh * 64 * 1024;
  int n0 = blockIdx.x * 64;
  int c = threadIdx.x & 63, r4 = threadIdx.x >> 6;
#pragma unroll
  for (int i = 0; i < 16; i++)
    tile[i * 4 + r4][c] = src[(long)(n0 + i * 4 + r4) * 2048 + c];
  __syncthreads();
#pragma unroll
  for (int i = 0; i < 16; i++)
    dst[(long)(i * 4 + r4) * 1024 + n0 + c] = tile[c][i * 4 + r4];
}

// ---------------- fused flash attention, swapped-QK^T in-register softmax ----------------
// grid (8 q-tiles, 64 bh), 256 thr. Wave w owns q-rows [w*32, w*32+32).
// Per K-chunk of 128:
//   S^T = mfma32x32x16(K, Q)  -> lane holds P[q=lane&31][64 of 128 k] in regs
//   online softmax fully in-register (one shfl_xor(32) per reduce)
//   P -> B-operand frags via cvt_pk_bf16 + v_permlane32_swap (no LDS round-trip)
//   O^T += mfma32x32x16(V^T, P)  -> acc cols = q = lane&31 (alpha/l lane-local)
// K/V double-buffered in LDS; K packed [64][128] (rows k&63, col d+64*(k>>6)),
// V^T [64 d][128 k]; both 16-slot XOR swizzle (2-way max on frag reads).
// Epilogue: O^T -> O via dead Qs region, coalesced 16B stores.
__global__ __launch_bounds__(256) void attn_fused(
    const bf16* __restrict__ Q,   // [4096][1024]
    const bf16* __restrict__ KV,  // [4096][2048], K at col h*64
    const bf16* __restrict__ Vt,  // [64 bh][64 d][1024 n]
    bf16* __restrict__ X) {       // [4096][1024]
  __shared__ __align__(16) bf16 Qs[128 * 64];      // 16KB, dead after qf load (epilogue reuse)
  __shared__ __align__(16) bf16 Ks[2][64 * 128];   // 32KB
  __shared__ __align__(16) bf16 Vs[2][64 * 128];   // 32KB
  int tid = threadIdx.x, wave = tid >> 6, lane = tid & 63;
  int l31 = lane & 31, h = lane >> 5;
  int bh = blockIdx.y, b = bh >> 4, hd = bh & 15;
  const bf16* Qb = Q + (long)b * 1048576 + hd * 64;   // ld 1024
  const bf16* Kb = KV + (long)b * 2097152 + hd * 64;  // ld 2048
  const bf16* Vb = Vt + (long)bh * 65536;             // ld 1024
  bf16* Xb = X + (long)b * 1048576 + hd * 64;         // ld 1024
  int q0 = blockIdx.x * 128;

  // per-thread staging coords (chunk-invariant)
  const bf16* gk[4];
  const bf16* gv[4];
  int eoKV[4];
#pragma unroll
  for (int t = 0; t < 4; t++) {
    int eo = (t * 256 + tid) * 8;
    eoKV[t] = eo;
    int r2 = eo >> 7, pp = (eo & 127) >> 3, q = pp ^ (r2 & 15);
    // K: LDS row r2 holds k in {r2, r2+64}; logical slot q: k-half = q>>3, d-chunk = q&7
    gk[t] = &Kb[(long)(r2 + ((q >> 3) << 6)) * 2048 + ((q & 7) << 3)];
    // V: LDS row r2 = d; logical slot q = k-chunk within 128
    gv[t] = &Vb[(long)r2 * 1024 + (q << 3)];
  }

  // prologue: stage Q (8-slot xor) + K/V chunk 0
#pragma unroll
  for (int t = 0; t < 4; t++) {
    int eo = (t * 256 + tid) * 8;
    int r = eo >> 6, p = (eo & 63) >> 3;
    int c = (p ^ (r & 7)) << 3;
    GLOAD_LDS16(&Qb[(long)(q0 + r) * 1024 + c], &Qs[eo]);
  }
#pragma unroll
  for (int t = 0; t < 4; t++) GLOAD_LDS16(gk[t], &Ks[0][eoKV[t]]);
#pragma unroll
  for (int t = 0; t < 4; t++) GLOAD_LDS16(gv[t], &Vs[0][eoKV[t]]);
  __syncthreads();

  // Q fragments (B-operand rows q = wave*32+l31), resident for whole kernel
  bf16x8 qf[4];
  {
    int r = wave * 32 + l31;
#pragma unroll
    for (int dw = 0; dw < 4; dw++) {
      int p = (dw * 2 + h) ^ (r & 7);
      qf[dw] = *(const bf16x8*)&Qs[r * 64 + p * 8];
    }
  }

  const float C = 0.18033688011112042f;  // SCALE * log2(e)
  float m_run = -1e30f, l_run = 0.0f;
  f32x16 acc[2] = {};
  int cur = 0;

  for (int kc = 0; kc < 8; kc++) {
    // issue next-chunk staging (overlaps compute; single barrier per chunk)
    if (kc < 7) {
#pragma unroll
      for (int t = 0; t < 4; t++)
        GLOAD_LDS16(gk[t] + (long)(kc + 1) * 128 * 2048, &Ks[cur ^ 1][eoKV[t]]);
#pragma unroll
      for (int t = 0; t < 4; t++)
        GLOAD_LDS16(gv[t] + (kc + 1) * 128, &Vs[cur ^ 1][eoKV[t]]);
    }
    const bf16* ks = Ks[cur];
    const bf16* vs = Vs[cur];

    // S^T tiles [32 k][32 q], 4 per chunk
    f32x16 s[4] = {};
#pragma unroll
    for (int kt = 0; kt < 4; kt++) {
      int k = kt * 32 + l31;
      int r2 = k & 63, hi = k >> 6;
#pragma unroll
      for (int dw = 0; dw < 4; dw++) {
        int p = (hi * 8 + dw * 2 + h) ^ (r2 & 15);
        bf16x8 kf = *(const bf16x8*)&ks[r2 * 128 + p * 8];
        s[kt] = __builtin_amdgcn_mfma_f32_32x32x16_bf16(kf, qf[dw], s[kt], 0, 0, 0);
      }
    }

    // online softmax: lane owns q = l31; regs hold 64 of 128 k (rest in lane^32)
    float mk[4];
#pragma unroll
    for (int kt = 0; kt < 4; kt++) {
      float m01 = fmaxf(fmaxf(s[kt][0], s[kt][1]), fmaxf(s[kt][2], s[kt][3]));
      float m23 = fmaxf(fmaxf(s[kt][4], s[kt][5]), fmaxf(s[kt][6], s[kt][7]));
      float m45 = fmaxf(fmaxf(s[kt][8], s[kt][9]), fmaxf(s[kt][10], s[kt][11]));
      float m67 = fmaxf(fmaxf(s[kt][12], s[kt][13]), fmaxf(s[kt][14], s[kt][15]));
      mk[kt] = fmaxf(fmaxf(m01, m23), fmaxf(m45, m67));
    }
    float mx = fmaxf(fmaxf(mk[0], mk[1]), fmaxf(mk[2], mk[3]));
    mx = fmaxf(mx, __shfl_xor(mx, 32));
    float m_new = fmaxf(m_run, mx);
    float alpha = exp2f((m_run - m_new) * C);
    m_run = m_new;
    float mc = m_new * C;
    float rk[4];
#pragma unroll
    for (int kt = 0; kt < 4; kt++) {
      float r0 = 0.0f;
#pragma unroll
      for (int r = 0; r < 16; r++) {
        float pv = exp2f(s[kt][r] * C - mc);
        s[kt][r] = pv;
        r0 += pv;
      }
      rk[kt] = r0;
    }
    float rs = (rk[0] + rk[1]) + (rk[2] + rk[3]);
    rs += __shfl_xor(rs, 32);
    l_run = l_run * alpha + rs;
#pragma unroll
    for (int nt = 0; nt < 2; nt++)
#pragma unroll
      for (int r = 0; r < 16; r++) acc[nt][r] *= alpha;

    // PV: per 16-k window, build P B-frag in-register (cvt_pk + 2 permlane swaps)
#pragma unroll
    for (int kw = 0; kw < 8; kw++) {
      int kt = kw >> 1, rb = (kw & 1) * 8;
      u32 wA = pk_bf16(s[kt][rb + 0], s[kt][rb + 1]);
      u32 wB = pk_bf16(s[kt][rb + 2], s[kt][rb + 3]);
      u32 wC = pk_bf16(s[kt][rb + 4], s[kt][rb + 5]);
      u32 wD = pk_bf16(s[kt][rb + 6], s[kt][rb + 7]);
      plane32_swap(wA, wC);  // wA -> frag word0, wC -> frag word2
      plane32_swap(wB, wD);  // wB -> frag word1, wD -> frag word3
      u32x4 wv = {wA, wB, wC, wD};
      bf16x8 pf = __builtin_bit_cast(bf16x8, wv);
#pragma unroll
      for (int nt = 0; nt < 2; nt++) {
        int r2 = nt * 32 + l31;
        int p = (kw * 2 + h) ^ (r2 & 15);
        bf16x8 vf = *(const bf16x8*)&vs[r2 * 128 + p * 8];
        // D = V^T . P^T = O^T : rows = d (crow), cols = q = lane&31
        acc[nt] = __builtin_amdgcn_mfma_f32_32x32x16_bf16(vf, pf, acc[nt], 0, 0, 0);
      }
    }

    if (kc < 7) {
      __syncthreads();  // drains vmcnt: next chunk staged; all reads of cur done
      cur ^= 1;
    }
  }

  // epilogue: O^T -> O via dead Qs region (wave-private rows, no barrier needed).
  // write: lane has O[q=l31][d = nt*32 + g*8 + 4h + 0..3]; 8B-slot xor(q&15) swizzle
  float fs = SCALE / l_run;  // second faithful SCALE folded with 1/l
  bf16* Os = Qs;
  int qrow = wave * 32 + l31;
#pragma unroll
  for (int nt = 0; nt < 2; nt++)
#pragma unroll
    for (int g = 0; g < 4; g++) {
      u32 w0 = pk_bf16(acc[nt][g * 4 + 0] * fs, acc[nt][g * 4 + 1] * fs);
      u32 w1 = pk_bf16(acc[nt][g * 4 + 2] * fs, acc[nt][g * 4 + 3] * fs);
      int s8 = nt * 8 + g * 2 + h;  // logical 8B slot = d/4
      int phys = s8 ^ (qrow & 15);
      u32x2 wv = {w0, w1};
      *(u32x2*)&Os[qrow * 64 + phys * 4] = wv;
    }
  // read back own wave's rows, store coalesced 16B
  int rrow = wave * 32 + (lane >> 1);
  int cbase = (lane & 1) * 32;
#pragma unroll
  for (int t2 = 0; t2 < 4; t2++) {
    int s0 = (lane & 1) * 8 + t2 * 2;
    u32x2 a = *(u32x2*)&Os[rrow * 64 + ((s0 ^ (rrow & 15)) * 4)];
    u32x2 bb = *(u32x2*)&Os[rrow * 64 + (((s0 + 1) ^ (rrow & 15)) * 4)];
    u32x4 o4 = {a[0], a[1], bb[0], bb[1]};
    *(u32x4*)&Xb[(long)(q0 + rrow) * 1024 + cbase + t2 * 8] = o4;
  }
}

// ---------------- templated C = A @ Bt^T (+epilogue) ----------------
// A[M,K] bf16 (lda), Bt[N,K] bf16 (ldb). z = (z>>4)*hi + (z&15)*lo strides.
// LDS XOR-swizzled (16B chunk p of row r holds logical chunk p^(r&7)).
// EPI: 0 = store bf16; 1 = acc+bias+res (CF32 fp32 C; RBF16 bf16 res);
//      2 = gelu(acc+bias) -> bf16
template <int BM, int BN, int BK, int WR, int WC, int EPI, int CF32, int RBF16>
__global__ __launch_bounds__(256) void gemm_t(
    const bf16* __restrict__ A, long sA_lo, long sA_hi, int lda,
    const bf16* __restrict__ B, long sB_lo, long sB_hi, int ldb,
    void* __restrict__ Cv, long sC_lo, long sC_hi, int ldc,
    int K,
    const float* __restrict__ bias,
    const void* __restrict__ resv, int ldr) {
  constexpr int MT = BM / (16 * WR);
  constexpr int NT = BN / (16 * WC);
  constexpr int KS = BK / 32;
  constexpr int ACH = BM * BK / 2048;
  constexpr int BCH = BN * BK / 2048;
  __shared__ __align__(16) bf16 As[BM * BK];
  __shared__ __align__(16) bf16 Bs[BN * BK];
  int tid = threadIdx.x;
  int wave = tid >> 6, lane = tid & 63;
  int wm = wave / WC, wn = wave % WC;
  int quad = lane >> 4, l16 = lane & 15;
  int zhi = blockIdx.z >> 4, zlo = blockIdx.z & 15;
  const bf16* Ab = A + zhi * sA_hi + zlo * sA_lo;
  const bf16* Bb = B + zhi * sB_hi + zlo * sB_lo;
  long coff = zhi * sC_hi + zlo * sC_lo;
  int m0 = blockIdx.y * BM, n0 = blockIdx.x * BN;

  f32x4 acc[MT][NT] = {};

  for (int kt = 0; kt < K; kt += BK) {
    __syncthreads();
#pragma unroll
    for (int t = 0; t < ACH; t++) {
      int eo = (t * 256 + tid) * 8;
      int r = eo / BK, p = (eo % BK) >> 3;
      int c = (p ^ (r & 7)) << 3;
      GLOAD_LDS16(&Ab[(long)(m0 + r) * lda + kt + c], &As[eo]);
    }
#pragma unroll
    for (int t = 0; t < BCH; t++) {
      int eo = (t * 256 + tid) * 8;
      int r = eo / BK, p = (eo % BK) >> 3;
      int c = (p ^ (r & 7)) << 3;
      GLOAD_LDS16(&Bb[(long)(n0 + r) * ldb + kt + c], &Bs[eo]);
    }
    __syncthreads();
    bf16x8 af[KS][MT], bfr[KS][NT];
#pragma unroll
    for (int ks = 0; ks < KS; ks++) {
#pragma unroll
      for (int mt = 0; mt < MT; mt++) {
        int row = wm * MT * 16 + mt * 16 + l16;
        int p = (ks * 4 + quad) ^ (row & 7);
        af[ks][mt] = *(const bf16x8*)&As[row * BK + p * 8];
      }
#pragma unroll
      for (int nt = 0; nt < NT; nt++) {
        int row = wn * NT * 16 + nt * 16 + l16;
        int p = (ks * 4 + quad) ^ (row & 7);
        bfr[ks][nt] = *(const bf16x8*)&Bs[row * BK + p * 8];
      }
    }
#pragma unroll
    for (int ks = 0; ks < KS; ks++)
#pragma unroll
      for (int mt = 0; mt < MT; mt++)
#pragma unroll
        for (int nt = 0; nt < NT; nt++)
          acc[mt][nt] = __builtin_amdgcn_mfma_f32_16x16x32_bf16(
              af[ks][mt], bfr[ks][nt], acc[mt][nt], 0, 0, 0);
  }

  int gm = m0 + wm * MT * 16, gn = n0 + wn * NT * 16;
#pragma unroll
  for (int nt = 0; nt < NT; nt++) {
    int col = gn + nt * 16 + l16;
    float bv = (EPI != 0) ? bias[col] : 0.0f;
#pragma unroll
    for (int mt = 0; mt < MT; mt++) {
#pragma unroll
      for (int r = 0; r < 4; r++) {
        int row = gm + mt * 16 + quad * 4 + r;
        float v = acc[mt][nt][r] + bv;
        if (EPI == 2) {
          v = 0.5f * v * (1.0f + erff(v * 0.70710678118654752f));
        } else if (EPI == 1) {
          float rv = RBF16 ? (float)((const bf16*)resv)[(long)row * ldr + col]
                           : ((const float*)resv)[(long)row * ldr + col];
          v += rv;
        }
        if (CF32)
          ((float*)Cv)[coff + (long)row * ldc + col] = v;
        else
          ((bf16*)Cv)[coff + (long)row * ldc + col] = (bf16)v;
      }
    }
  }
}

extern "C" void kernel_launch(void* const* d_in, const int* in_sizes, int n_in,
                              void* d_out, int out_size, void* d_ws, size_t ws_size,
                              hipStream_t stream) {
  const float* src_q  = (const float*)d_in[0];
  const float* src_kv = (const float*)d_in[1];
  const float* gq     = (const float*)d_in[2];
  const float* bq     = (const float*)d_in[3];
  const float* gkv    = (const float*)d_in[4];
  const float* bkv    = (const float*)d_in[5];
  const float* Wq     = (const float*)d_in[6];
  const float* Wkv    = (const float*)d_in[7];
  const float* Wproj  = (const float*)d_in[8];
  const float* bproj  = (const float*)d_in[9];
  const float* gn     = (const float*)d_in[10];
  const float* bn     = (const float*)d_in[11];
  const float* W1     = (const float*)d_in[12];
  const float* b1     = (const float*)d_in[13];
  const float* W2     = (const float*)d_in[14];
  const float* b2     = (const float*)d_in[15];
  float* out = (float*)d_out;

  char* ws = (char*)d_ws;
  const long MB = 1024 * 1024;
  bf16* Wq_t    = (bf16*)(ws + 0 * MB);    // [1024][1024]  2MB   (whole run)
  bf16* Wkv_t   = (bf16*)(ws + 2 * MB);    // [2048][1024]  4MB
  bf16* Wproj_t = (bf16*)(ws + 6 * MB);    // [1024][1024]  2MB
  bf16* W1_t    = (bf16*)(ws + 8 * MB);    // [4096][1024]  8MB
  bf16* W2_t    = (bf16*)(ws + 16 * MB);   // [1024][4096]  8MB  (ld = 4096!)
  bf16* qn      = (bf16*)(ws + 24 * MB);   // [4096][1024]  8MB   dead after Q GEMM
  bf16* kvn     = (bf16*)(ws + 32 * MB);   // [4096][1024]  8MB   dead after KV GEMM
  bf16* Qm      = (bf16*)(ws + 40 * MB);   // [4096][1024]  8MB   dead after attn
  bf16* KVm     = (bf16*)(ws + 48 * MB);   // [4096][2048] 16MB   dead after attn
  bf16* Vt      = (bf16*)(ws + 64 * MB);   // [64][64][1024] 8MB  dead after attn
  bf16* xbuf    = (bf16*)(ws + 24 * MB);   // [4096][1024]  8MB   (reuses qn)
  float* tbuf   = (float*)(ws + 48 * MB);  // [4096][1024] 16MB fp32 (reuses KVm)
  bf16* sbuf    = (bf16*)(ws + 64 * MB);   // [4096][1024]  8MB   (reuses Vt)
  bf16* hbuf    = (bf16*)(ws + 72 * MB);   // [4096][4096] 32MB

  // weight transposes (fp32 -> bf16)
  transpose_w<<<dim3(16, 16), 256, 0, stream>>>(Wq, Wq_t, 1024, 1024);
  transpose_w<<<dim3(32, 16), 256, 0, stream>>>(Wkv, Wkv_t, 1024, 2048);
  transpose_w<<<dim3(16, 16), 256, 0, stream>>>(Wproj, Wproj_t, 1024, 1024);
  transpose_w<<<dim3(64, 16), 256, 0, stream>>>(W1, W1_t, 1024, 4096);
  transpose_w<<<dim3(16, 64), 256, 0, stream>>>(W2, W2_t, 4096, 1024);

  // LayerNorms (fp32 -> bf16)
  ln_f32<<<4096, 256, 0, stream>>>(src_q, gq, bq, qn);
  ln_f32<<<4096, 256, 0, stream>>>(src_kv, gkv, bkv, kvn);

  // Q = qn @ Wq   (N=1024 -> BN=64 config, 512 blocks)
  gemm_t<128, 64, 64, 4, 1, 0, 0, 0><<<dim3(16, 32, 1), 256, 0, stream>>>(
      qn, 0, 0, 1024, Wq_t, 0, 0, 1024, Qm, 0, 0, 1024, 1024,
      nullptr, nullptr, 0);
  // KV = kvn @ Wkv  (N=2048, 128x128 tiles, 512 blocks)
  gemm_t<128, 128, 64, 2, 2, 0, 0, 0><<<dim3(16, 32, 1), 256, 0, stream>>>(
      kvn, 0, 0, 1024, Wkv_t, 0, 0, 1024, KVm, 0, 0, 2048, 1024,
      nullptr, nullptr, 0);
  extract_vt<<<dim3(16, 1, 64), 256, 0, stream>>>(KVm, Vt);

  // fused flash attention: 8 q-tiles x 64 bh, 512 blocks (2/CU at 80KB LDS)
  attn_fused<<<dim3(8, 64), 256, 0, stream>>>(Qm, KVm, Vt, xbuf);

  // tbuf = src_q + x @ Wproj + bproj   (fp32 out, N=1024 -> BN=64)
  gemm_t<128, 64, 64, 4, 1, 1, 1, 0><<<dim3(16, 32, 1), 256, 0, stream>>>(
      xbuf, 0, 0, 1024, Wproj_t, 0, 0, 1024, tbuf, 0, 0, 1024, 1024,
      bproj, src_q, 1024);
  // sbuf = LN(tbuf)  (bf16 out)
  ln_f32<<<4096, 256, 0, stream>>>(tbuf, gn, bn, sbuf);
  // hbuf = gelu(sbuf @ W1 + b1)  (bf16 out, N=4096)
  gemm_t<128, 128, 64, 2, 2, 2, 0, 0><<<dim3(32, 32, 1), 256, 0, stream>>>(
      sbuf, 0, 0, 1024, W1_t, 0, 0, 1024, hbuf, 0, 0, 4096, 1024,
      b1, nullptr, 0);
  // out = sbuf + hbuf @ W2 + b2  (fp32 out, N=1024 -> BN=64, K=4096; ldb=4096)
  gemm_t<128, 64, 64, 4, 1, 1, 1, 1><<<dim3(16, 32, 1), 256, 0, stream>>>(
      hbuf, 0, 0, 4096, W2_t, 0, 0, 4096, out, 0, 0, 1024, 4096,
      b2, sbuf, 1024);
}

// Round 2
// 371.970 us; speedup vs baseline: 1.1723x; 1.0899x over previous
//
#include <hip/hip_runtime.h>
#include <hip/hip_bf16.h>
#include <math.h>

typedef __bf16 bf16;
typedef __bf16 bf16x2 __attribute__((ext_vector_type(2)));
typedef __bf16 bf16x8 __attribute__((ext_vector_type(8)));
typedef float f32x4 __attribute__((ext_vector_type(4)));
typedef float f32x16 __attribute__((ext_vector_type(16)));
typedef unsigned int u32;
typedef unsigned int u32x2 __attribute__((ext_vector_type(2)));
typedef unsigned int u32x4 __attribute__((ext_vector_type(4)));

#define SCALE 0.125f

// async global->LDS, 16B per lane. LDS dest must be wave-uniform base + lane*16.
#define GLOAD_LDS16(gptr, lptr)                                      \
  __builtin_amdgcn_global_load_lds(                                  \
      (const __attribute__((address_space(1))) void*)(gptr),         \
      (__attribute__((address_space(3))) void*)(lptr), 16, 0, 0)

template <int N>
__device__ __forceinline__ void vmcnt_wait() {
  if constexpr (N == 0) asm volatile("s_waitcnt vmcnt(0)" ::: "memory");
  else if constexpr (N == 4) asm volatile("s_waitcnt vmcnt(4)" ::: "memory");
  else if constexpr (N == 6) asm volatile("s_waitcnt vmcnt(6)" ::: "memory");
  else static_assert(N == 0 || N == 4 || N == 6, "unsupported vmcnt");
}

// pack two f32 -> one u32 of 2 bf16 (RNE); compiler emits v_cvt_pk_bf16_f32
__device__ __forceinline__ u32 pk_bf16(float lo, float hi) {
  bf16x2 t;
  t[0] = (bf16)lo;
  t[1] = (bf16)hi;
  return __builtin_bit_cast(u32, t);
}

// v_permlane32_swap_b32: a.hi <-> b.lo
__device__ __forceinline__ void plane32_swap(u32& a, u32& b) {
  asm volatile("v_permlane32_swap_b32 %0, %1" : "+v"(a), "+v"(b));
}

// ---------------- row LayerNorm: fp32 in -> bf16 out, one block per row of 1024 ----------------
__global__ __launch_bounds__(256) void ln_f32(const float* __restrict__ x,
                                              const float* __restrict__ g,
                                              const float* __restrict__ b,
                                              bf16* __restrict__ y) {
  long base = (long)blockIdx.x * 1024;
  int tid = threadIdx.x;
  float v[4];
#pragma unroll
  for (int i = 0; i < 4; i++) v[i] = x[base + tid + i * 256];
  float s1 = v[0] + v[1] + v[2] + v[3];
  float s2 = v[0] * v[0] + v[1] * v[1] + v[2] * v[2] + v[3] * v[3];
#pragma unroll
  for (int off = 32; off; off >>= 1) {
    s1 += __shfl_xor(s1, off);
    s2 += __shfl_xor(s2, off);
  }
  __shared__ float aux[2][4];
  int wave = tid >> 6, lane = tid & 63;
  if (lane == 0) { aux[0][wave] = s1; aux[1][wave] = s2; }
  __syncthreads();
  float S1 = aux[0][0] + aux[0][1] + aux[0][2] + aux[0][3];
  float S2 = aux[1][0] + aux[1][1] + aux[1][2] + aux[1][3];
  float mean = S1 * (1.0f / 1024.0f);
  float var = S2 * (1.0f / 1024.0f) - mean * mean;
  float rs = rsqrtf(var + 1e-5f);
#pragma unroll
  for (int i = 0; i < 4; i++) {
    int c = tid + i * 256;
    y[base + c] = (bf16)(((v[i] - mean) * rs) * g[c] + b[c]);
  }
}

// ---------------- W[K][N] fp32 -> Wt[N][K] bf16 tiled transpose ----------------
__global__ __launch_bounds__(256) void transpose_w(const float* __restrict__ W,
                                                   bf16* __restrict__ Wt,
                                                   int K, int N) {
  __shared__ bf16 tile[64][66];
  int n0 = blockIdx.x * 64, k0 = blockIdx.y * 64;
  int c = threadIdx.x & 63, r4 = threadIdx.x >> 6;
#pragma unroll
  for (int i = 0; i < 16; i++)
    tile[i * 4 + r4][c] = (bf16)W[(long)(k0 + i * 4 + r4) * N + n0 + c];
  __syncthreads();
#pragma unroll
  for (int i = 0; i < 16; i++)
    Wt[(long)(n0 + i * 4 + r4) * K + k0 + c] = tile[c][i * 4 + r4];
}

// ------- extract V^T per (b,h): Vt[bh][d][n] = KV[b*1024+n][1024 + h*64 + d] (bf16) -------
__global__ __launch_bounds__(256) void extract_vt(const bf16* __restrict__ KV,
                                                  bf16* __restrict__ Vt) {
  __shared__ bf16 tile[64][66];
  int bh = blockIdx.z, b = bh >> 4, h = bh & 15;
  const bf16* src = KV + (long)b * 1024 * 2048 + 1024 + h * 64;
  bf16* dst = Vt + (long)bh * 64 * 1024;
  int n0 = blockIdx.x * 64;
  int c = threadIdx.x & 63, r4 = threadIdx.x >> 6;
#pragma unroll
  for (int i = 0; i < 16; i++)
    tile[i * 4 + r4][c] = src[(long)(n0 + i * 4 + r4) * 2048 + c];
  __syncthreads();
#pragma unroll
  for (int i = 0; i < 16; i++)
    dst[(long)(i * 4 + r4) * 1024 + n0 + c] = tile[c][i * 4 + r4];
}

// ---------------- fused flash attention, swapped-QK^T in-register softmax ----------------
__global__ __launch_bounds__(256) void attn_fused(
    const bf16* __restrict__ Q,   // [4096][1024]
    const bf16* __restrict__ KV,  // [4096][2048], K at col h*64
    const bf16* __restrict__ Vt,  // [64 bh][64 d][1024 n]
    bf16* __restrict__ X) {       // [4096][1024]
  __shared__ __align__(16) bf16 Qs[128 * 64];      // 16KB, dead after qf load (epilogue reuse)
  __shared__ __align__(16) bf16 Ks[2][64 * 128];   // 32KB
  __shared__ __align__(16) bf16 Vs[2][64 * 128];   // 32KB
  int tid = threadIdx.x, wave = tid >> 6, lane = tid & 63;
  int l31 = lane & 31, h = lane >> 5;
  int bh = blockIdx.y, b = bh >> 4, hd = bh & 15;
  const bf16* Qb = Q + (long)b * 1048576 + hd * 64;   // ld 1024
  const bf16* Kb = KV + (long)b * 2097152 + hd * 64;  // ld 2048
  const bf16* Vb = Vt + (long)bh * 65536;             // ld 1024
  bf16* Xb = X + (long)b * 1048576 + hd * 64;         // ld 1024
  int q0 = blockIdx.x * 128;

  // per-thread staging coords (chunk-invariant)
  const bf16* gk[4];
  const bf16* gv[4];
  int eoKV[4];
#pragma unroll
  for (int t = 0; t < 4; t++) {
    int eo = (t * 256 + tid) * 8;
    eoKV[t] = eo;
    int r2 = eo >> 7, pp = (eo & 127) >> 3, q = pp ^ (r2 & 15);
    gk[t] = &Kb[(long)(r2 + ((q >> 3) << 6)) * 2048 + ((q & 7) << 3)];
    gv[t] = &Vb[(long)r2 * 1024 + (q << 3)];
  }

  // prologue: stage Q (8-slot xor) + K/V chunk 0
#pragma unroll
  for (int t = 0; t < 4; t++) {
    int eo = (t * 256 + tid) * 8;
    int r = eo >> 6, p = (eo & 63) >> 3;
    int c = (p ^ (r & 7)) << 3;
    GLOAD_LDS16(&Qb[(long)(q0 + r) * 1024 + c], &Qs[eo]);
  }
#pragma unroll
  for (int t = 0; t < 4; t++) GLOAD_LDS16(gk[t], &Ks[0][eoKV[t]]);
#pragma unroll
  for (int t = 0; t < 4; t++) GLOAD_LDS16(gv[t], &Vs[0][eoKV[t]]);
  __syncthreads();

  // Q fragments (B-operand rows q = wave*32+l31), resident for whole kernel
  bf16x8 qf[4];
  {
    int r = wave * 32 + l31;
#pragma unroll
    for (int dw = 0; dw < 4; dw++) {
      int p = (dw * 2 + h) ^ (r & 7);
      qf[dw] = *(const bf16x8*)&Qs[r * 64 + p * 8];
    }
  }

  const float C = 0.18033688011112042f;  // SCALE * log2(e)
  float m_run = -1e30f, l_run = 0.0f;
  f32x16 acc[2] = {};
  int cur = 0;

  for (int kc = 0; kc < 8; kc++) {
    if (kc < 7) {
#pragma unroll
      for (int t = 0; t < 4; t++)
        GLOAD_LDS16(gk[t] + (long)(kc + 1) * 128 * 2048, &Ks[cur ^ 1][eoKV[t]]);
#pragma unroll
      for (int t = 0; t < 4; t++)
        GLOAD_LDS16(gv[t] + (kc + 1) * 128, &Vs[cur ^ 1][eoKV[t]]);
    }
    const bf16* ks = Ks[cur];
    const bf16* vs = Vs[cur];

    // S^T tiles [32 k][32 q], 4 per chunk
    f32x16 s[4] = {};
#pragma unroll
    for (int kt = 0; kt < 4; kt++) {
      int k = kt * 32 + l31;
      int r2 = k & 63, hi = k >> 6;
#pragma unroll
      for (int dw = 0; dw < 4; dw++) {
        int p = (hi * 8 + dw * 2 + h) ^ (r2 & 15);
        bf16x8 kf = *(const bf16x8*)&ks[r2 * 128 + p * 8];
        s[kt] = __builtin_amdgcn_mfma_f32_32x32x16_bf16(kf, qf[dw], s[kt], 0, 0, 0);
      }
    }

    // online softmax: lane owns q = l31; regs hold 64 of 128 k (rest in lane^32)
    float mk[4];
#pragma unroll
    for (int kt = 0; kt < 4; kt++) {
      float m01 = fmaxf(fmaxf(s[kt][0], s[kt][1]), fmaxf(s[kt][2], s[kt][3]));
      float m23 = fmaxf(fmaxf(s[kt][4], s[kt][5]), fmaxf(s[kt][6], s[kt][7]));
      float m45 = fmaxf(fmaxf(s[kt][8], s[kt][9]), fmaxf(s[kt][10], s[kt][11]));
      float m67 = fmaxf(fmaxf(s[kt][12], s[kt][13]), fmaxf(s[kt][14], s[kt][15]));
      mk[kt] = fmaxf(fmaxf(m01, m23), fmaxf(m45, m67));
    }
    float mx = fmaxf(fmaxf(mk[0], mk[1]), fmaxf(mk[2], mk[3]));
    mx = fmaxf(mx, __shfl_xor(mx, 32));
    float m_new = fmaxf(m_run, mx);
    float alpha = exp2f((m_run - m_new) * C);
    m_run = m_new;
    float mc = m_new * C;
    float rk[4];
#pragma unroll
    for (int kt = 0; kt < 4; kt++) {
      float r0 = 0.0f;
#pragma unroll
      for (int r = 0; r < 16; r++) {
        float pv = exp2f(s[kt][r] * C - mc);
        s[kt][r] = pv;
        r0 += pv;
      }
      rk[kt] = r0;
    }
    float rs = (rk[0] + rk[1]) + (rk[2] + rk[3]);
    rs += __shfl_xor(rs, 32);
    l_run = l_run * alpha + rs;
#pragma unroll
    for (int nt = 0; nt < 2; nt++)
#pragma unroll
      for (int r = 0; r < 16; r++) acc[nt][r] *= alpha;

    // PV: per 16-k window, build P B-frag in-register (cvt_pk + 2 permlane swaps)
#pragma unroll
    for (int kw = 0; kw < 8; kw++) {
      int kt = kw >> 1, rb = (kw & 1) * 8;
      u32 wA = pk_bf16(s[kt][rb + 0], s[kt][rb + 1]);
      u32 wB = pk_bf16(s[kt][rb + 2], s[kt][rb + 3]);
      u32 wC = pk_bf16(s[kt][rb + 4], s[kt][rb + 5]);
      u32 wD = pk_bf16(s[kt][rb + 6], s[kt][rb + 7]);
      plane32_swap(wA, wC);
      plane32_swap(wB, wD);
      u32x4 wv = {wA, wB, wC, wD};
      bf16x8 pf = __builtin_bit_cast(bf16x8, wv);
#pragma unroll
      for (int nt = 0; nt < 2; nt++) {
        int r2 = nt * 32 + l31;
        int p = (kw * 2 + h) ^ (r2 & 15);
        bf16x8 vf = *(const bf16x8*)&vs[r2 * 128 + p * 8];
        acc[nt] = __builtin_amdgcn_mfma_f32_32x32x16_bf16(vf, pf, acc[nt], 0, 0, 0);
      }
    }

    if (kc < 7) {
      __syncthreads();
      cur ^= 1;
    }
  }

  // epilogue: O^T -> O via dead Qs region (wave-private rows, no barrier needed).
  float fs = SCALE / l_run;  // second faithful SCALE folded with 1/l
  bf16* Os = Qs;
  int qrow = wave * 32 + l31;
#pragma unroll
  for (int nt = 0; nt < 2; nt++)
#pragma unroll
    for (int g = 0; g < 4; g++) {
      u32 w0 = pk_bf16(acc[nt][g * 4 + 0] * fs, acc[nt][g * 4 + 1] * fs);
      u32 w1 = pk_bf16(acc[nt][g * 4 + 2] * fs, acc[nt][g * 4 + 3] * fs);
      int s8 = nt * 8 + g * 2 + h;
      int phys = s8 ^ (qrow & 15);
      u32x2 wv = {w0, w1};
      *(u32x2*)&Os[qrow * 64 + phys * 4] = wv;
    }
  int rrow = wave * 32 + (lane >> 1);
  int cbase = (lane & 1) * 32;
#pragma unroll
  for (int t2 = 0; t2 < 4; t2++) {
    int s0 = (lane & 1) * 8 + t2 * 2;
    u32x2 a = *(u32x2*)&Os[rrow * 64 + ((s0 ^ (rrow & 15)) * 4)];
    u32x2 bb = *(u32x2*)&Os[rrow * 64 + (((s0 + 1) ^ (rrow & 15)) * 4)];
    u32x4 o4 = {a[0], a[1], bb[0], bb[1]};
    *(u32x4*)&Xb[(long)(q0 + rrow) * 1024 + cbase + t2 * 8] = o4;
  }
}

// ---------------- pipelined C = A @ Bt^T (+epilogue), triple-buffered, counted vmcnt ----------------
// A[M,K] bf16 (lda), Bt[N,K] bf16 (ldb). BK=64 fixed. 512 threads = 8 waves (WR x WC).
// LDS: 3 tile-buffers, each A[BM][64] + B[BN][64], rows 128B, 16B-slot p -> p^(row&7)
// (proven 0-conflict). Tile t -> buffer t%3; tile t+2 staged during tile t's phases;
// vmcnt(L) at end of tile t retires exactly tile t+1's L loads (never 0 in steady state).
// Per phase: {ds_read frags | issue prefetch | [vmcnt] | s_barrier | lgkmcnt(0) |
//             sched_barrier | setprio(1) MFMA setprio(0) | s_barrier}.
// EPI: 0 = store bf16; 1 = acc+bias+res (CF32 fp32 C; RBF16 bf16 res); 2 = gelu -> bf16
template <int BM, int BN, int WR, int WC, int PH, int EPI, int CF32, int RBF16>
__global__ __launch_bounds__(512) void gemm_p(
    const bf16* __restrict__ A, int lda,
    const bf16* __restrict__ B, int ldb,
    void* __restrict__ Cv, int ldc, int K,
    const float* __restrict__ bias,
    const void* __restrict__ resv, int ldr) {
  constexpr int MT = BM / (16 * WR);
  constexpr int NT = BN / (16 * WC);
  constexpr int KSP = 2 / PH;            // MFMA K-steps (of 32) per phase
  constexpr int L = (BM + BN) / 64;      // gloads/thread/tile
  constexpr int LA = BM / 64;
  constexpr int AE = BM * 64;
  constexpr int BUFE = (BM + BN) * 64;
  __shared__ __align__(16) bf16 lds[3 * BUFE];
  int tid = threadIdx.x;
  int wave = tid >> 6, lane = tid & 63;
  int wm = wave / WC, wn = wave % WC;
  int quad = lane >> 4, l16 = lane & 15;
  int m0 = blockIdx.y * BM, n0 = blockIdx.x * BN;

  // per-thread staging descriptors (compile-time indexed -> registers)
  const bf16* gp[L];
  int lo[L];
#pragma unroll
  for (int i = 0; i < L; i++) {
    if (i < LA) {
      int eo = (i * 512 + tid) * 8;
      int r = eo >> 6, p = (eo & 63) >> 3;
      int c = (p ^ (r & 7)) << 3;
      gp[i] = &A[(long)(m0 + r) * lda + c];
      lo[i] = eo;
    } else {
      int eo = ((i - LA) * 512 + tid) * 8;
      int r = eo >> 6, p = (eo & 63) >> 3;
      int c = (p ^ (r & 7)) << 3;
      gp[i] = &B[(long)(n0 + r) * ldb + c];
      lo[i] = AE + eo;
    }
  }

  int ntk = K >> 6;
  // prologue: stage tiles 0 and 1; wait tile 0 (vmcnt keeps tile 1 in flight)
#pragma unroll
  for (int i = 0; i < L; i++) GLOAD_LDS16(gp[i], &lds[lo[i]]);
#pragma unroll
  for (int i = 0; i < L; i++) gp[i] += 64;
#pragma unroll
  for (int i = 0; i < L; i++) GLOAD_LDS16(gp[i], &lds[BUFE + lo[i]]);
#pragma unroll
  for (int i = 0; i < L; i++) gp[i] += 64;  // gp now at tile 2
  vmcnt_wait<L>();
  asm volatile("" ::: "memory");
  __builtin_amdgcn_s_barrier();

  f32x4 acc[MT][NT] = {};
  int b = 0;
  for (int t = 0; t < ntk; t++) {
    const bf16* Al = &lds[b * BUFE];
    const bf16* Bl = &lds[b * BUFE + AE];
    int b2 = b + 2; if (b2 >= 3) b2 -= 3;
    bool more = (t + 2) < ntk;
#pragma unroll
    for (int ph = 0; ph < PH; ph++) {
      bf16x8 af[KSP][MT], bv[KSP][NT];
#pragma unroll
      for (int k2 = 0; k2 < KSP; k2++) {
        int ks = ph * KSP + k2;
#pragma unroll
        for (int mt = 0; mt < MT; mt++) {
          int row = wm * (BM / WR) + mt * 16 + l16;
          int p = (ks * 4 + quad) ^ (row & 7);
          af[k2][mt] = *(const bf16x8*)&Al[row * 64 + p * 8];
        }
#pragma unroll
        for (int nt = 0; nt < NT; nt++) {
          int row = wn * (BN / WC) + nt * 16 + l16;
          int p = (ks * 4 + quad) ^ (row & 7);
          bv[k2][nt] = *(const bf16x8*)&Bl[row * 64 + p * 8];
        }
      }
      if (more) {
#pragma unroll
        for (int i = ph * L / PH; i < (ph + 1) * L / PH; i++)
          GLOAD_LDS16(gp[i], &lds[b2 * BUFE + lo[i]]);
      }
      if (ph == PH - 1) {
        if (more) vmcnt_wait<L>();
        else vmcnt_wait<0>();
      }
      asm volatile("" ::: "memory");
      __builtin_amdgcn_s_barrier();
      asm volatile("s_waitcnt lgkmcnt(0)" ::: "memory");
      __builtin_amdgcn_sched_barrier(0);
      __builtin_amdgcn_s_setprio(1);
#pragma unroll
      for (int k2 = 0; k2 < KSP; k2++)
#pragma unroll
        for (int mt = 0; mt < MT; mt++)
#pragma unroll
          for (int nt = 0; nt < NT; nt++)
            acc[mt][nt] = __builtin_amdgcn_mfma_f32_16x16x32_bf16(
                af[k2][mt], bv[k2][nt], acc[mt][nt], 0, 0, 0);
      __builtin_amdgcn_s_setprio(0);
      __builtin_amdgcn_sched_barrier(0);
      __builtin_amdgcn_s_barrier();
    }
#pragma unroll
    for (int i = 0; i < L; i++) gp[i] += 64;
    b += 1; if (b == 3) b = 0;
  }

  // epilogue (registers only; no barrier needed)
  int gm = m0 + wm * (BM / WR), gn = n0 + wn * (BN / WC);
#pragma unroll
  for (int nt = 0; nt < NT; nt++) {
    int col = gn + nt * 16 + l16;
    float bvb = (EPI != 0) ? bias[col] : 0.0f;
#pragma unroll
    for (int mt = 0; mt < MT; mt++) {
#pragma unroll
      for (int r = 0; r < 4; r++) {
        int row = gm + mt * 16 + quad * 4 + r;
        float v = acc[mt][nt][r] + bvb;
        if (EPI == 2) {
          v = 0.5f * v * (1.0f + erff(v * 0.70710678118654752f));
        } else if (EPI == 1) {
          float rv = RBF16 ? (float)((const bf16*)resv)[(long)row * ldr + col]
                           : ((const float*)resv)[(long)row * ldr + col];
          v += rv;
        }
        if (CF32)
          ((float*)Cv)[(long)row * ldc + col] = v;
        else
          ((bf16*)Cv)[(long)row * ldc + col] = (bf16)v;
      }
    }
  }
}

extern "C" void kernel_launch(void* const* d_in, const int* in_sizes, int n_in,
                              void* d_out, int out_size, void* d_ws, size_t ws_size,
                              hipStream_t stream) {
  const float* src_q  = (const float*)d_in[0];
  const float* src_kv = (const float*)d_in[1];
  const float* gq     = (const float*)d_in[2];
  const float* bq     = (const float*)d_in[3];
  const float* gkv    = (const float*)d_in[4];
  const float* bkv    = (const float*)d_in[5];
  const float* Wq     = (const float*)d_in[6];
  const float* Wkv    = (const float*)d_in[7];
  const float* Wproj  = (const float*)d_in[8];
  const float* bproj  = (const float*)d_in[9];
  const float* gn     = (const float*)d_in[10];
  const float* bn     = (const float*)d_in[11];
  const float* W1     = (const float*)d_in[12];
  const float* b1     = (const float*)d_in[13];
  const float* W2     = (const float*)d_in[14];
  const float* b2     = (const float*)d_in[15];
  float* out = (float*)d_out;

  char* ws = (char*)d_ws;
  const long MB = 1024 * 1024;
  bf16* Wq_t    = (bf16*)(ws + 0 * MB);    // [1024][1024]  2MB   (whole run)
  bf16* Wkv_t   = (bf16*)(ws + 2 * MB);    // [2048][1024]  4MB
  bf16* Wproj_t = (bf16*)(ws + 6 * MB);    // [1024][1024]  2MB
  bf16* W1_t    = (bf16*)(ws + 8 * MB);    // [4096][1024]  8MB
  bf16* W2_t    = (bf16*)(ws + 16 * MB);   // [1024][4096]  8MB  (ld = 4096!)
  bf16* qn      = (bf16*)(ws + 24 * MB);   // [4096][1024]  8MB   dead after Q GEMM
  bf16* kvn     = (bf16*)(ws + 32 * MB);   // [4096][1024]  8MB   dead after KV GEMM
  bf16* Qm      = (bf16*)(ws + 40 * MB);   // [4096][1024]  8MB   dead after attn
  bf16* KVm     = (bf16*)(ws + 48 * MB);   // [4096][2048] 16MB   dead after attn
  bf16* Vt      = (bf16*)(ws + 64 * MB);   // [64][64][1024] 8MB  dead after attn
  bf16* xbuf    = (bf16*)(ws + 24 * MB);   // [4096][1024]  8MB   (reuses qn)
  float* tbuf   = (float*)(ws + 48 * MB);  // [4096][1024] 16MB fp32 (reuses KVm)
  bf16* sbuf    = (bf16*)(ws + 64 * MB);   // [4096][1024]  8MB   (reuses Vt)
  bf16* hbuf    = (bf16*)(ws + 72 * MB);   // [4096][4096] 32MB

  // weight transposes (fp32 -> bf16)
  transpose_w<<<dim3(16, 16), 256, 0, stream>>>(Wq, Wq_t, 1024, 1024);
  transpose_w<<<dim3(32, 16), 256, 0, stream>>>(Wkv, Wkv_t, 1024, 2048);
  transpose_w<<<dim3(16, 16), 256, 0, stream>>>(Wproj, Wproj_t, 1024, 1024);
  transpose_w<<<dim3(64, 16), 256, 0, stream>>>(W1, W1_t, 1024, 4096);
  transpose_w<<<dim3(16, 64), 256, 0, stream>>>(W2, W2_t, 4096, 1024);

  // LayerNorms (fp32 -> bf16)
  ln_f32<<<4096, 256, 0, stream>>>(src_q, gq, bq, qn);
  ln_f32<<<4096, 256, 0, stream>>>(src_kv, gkv, bkv, kvn);

  // Q = qn @ Wq   (M=4096, N=1024, K=1024): 128x128, 256 blocks
  gemm_p<128, 128, 2, 4, 1, 0, 0, 0><<<dim3(8, 32), 512, 0, stream>>>(
      qn, 1024, Wq_t, 1024, Qm, 1024, 1024, nullptr, nullptr, 0);
  // KV = kvn @ Wkv  (M=4096, N=2048, K=1024): 256x128, 256 blocks
  gemm_p<256, 128, 4, 2, 2, 0, 0, 0><<<dim3(16, 16), 512, 0, stream>>>(
      kvn, 1024, Wkv_t, 1024, KVm, 2048, 1024, nullptr, nullptr, 0);
  extract_vt<<<dim3(16, 1, 64), 256, 0, stream>>>(KVm, Vt);

  // fused flash attention: 8 q-tiles x 64 bh, 512 blocks
  attn_fused<<<dim3(8, 64), 256, 0, stream>>>(Qm, KVm, Vt, xbuf);

  // tbuf = src_q + x @ Wproj + bproj   (fp32 out): 128x128, 256 blocks
  gemm_p<128, 128, 2, 4, 1, 1, 1, 0><<<dim3(8, 32), 512, 0, stream>>>(
      xbuf, 1024, Wproj_t, 1024, tbuf, 1024, 1024, bproj, src_q, 1024);
  // sbuf = LN(tbuf)  (bf16 out)
  ln_f32<<<4096, 256, 0, stream>>>(tbuf, gn, bn, sbuf);
  // hbuf = gelu(sbuf @ W1 + b1)  (bf16 out, N=4096): 256x128, 512 blocks
  gemm_p<256, 128, 4, 2, 2, 2, 0, 0><<<dim3(32, 16), 512, 0, stream>>>(
      sbuf, 1024, W1_t, 1024, hbuf, 4096, 1024, b1, nullptr, 0);
  // out = sbuf + hbuf @ W2 + b2  (fp32 out, K=4096): 128x128, 256 blocks
  gemm_p<128, 128, 2, 4, 1, 1, 1, 1><<<dim3(8, 32), 512, 0, stream>>>(
      hbuf, 4096, W2_t, 4096, out, 1024, 4096, b2, sbuf, 1024);
}

// Round 3
// 368.375 us; speedup vs baseline: 1.1837x; 1.0098x over previous
//
#include <hip/hip_runtime.h>
#include <hip/hip_bf16.h>
#include <math.h>

typedef __bf16 bf16;
typedef __bf16 bf16x2 __attribute__((ext_vector_type(2)));
typedef __bf16 bf16x8 __attribute__((ext_vector_type(8)));
typedef float f32x4 __attribute__((ext_vector_type(4)));
typedef float f32x16 __attribute__((ext_vector_type(16)));
typedef unsigned int u32;
typedef unsigned int u32x2 __attribute__((ext_vector_type(2)));
typedef unsigned int u32x4 __attribute__((ext_vector_type(4)));

#define SCALE 0.125f

// async global->LDS, 16B per lane. LDS dest must be wave-uniform base + lane*16.
#define GLOAD_LDS16(gptr, lptr)                                      \
  __builtin_amdgcn_global_load_lds(                                  \
      (const __attribute__((address_space(1))) void*)(gptr),         \
      (__attribute__((address_space(3))) void*)(lptr), 16, 0, 0)

template <int N>
__device__ __forceinline__ void vmcnt_wait() {
  if constexpr (N == 0) asm volatile("s_waitcnt vmcnt(0)" ::: "memory");
  else if constexpr (N == 4) asm volatile("s_waitcnt vmcnt(4)" ::: "memory");
  else if constexpr (N == 6) asm volatile("s_waitcnt vmcnt(6)" ::: "memory");
  else static_assert(N == 0 || N == 4 || N == 6, "unsupported vmcnt");
}

// pack two f32 -> one u32 of 2 bf16 (RNE); compiler emits v_cvt_pk_bf16_f32
__device__ __forceinline__ u32 pk_bf16(float lo, float hi) {
  bf16x2 t;
  t[0] = (bf16)lo;
  t[1] = (bf16)hi;
  return __builtin_bit_cast(u32, t);
}

// v_permlane32_swap_b32: a.hi <-> b.lo
__device__ __forceinline__ void plane32_swap(u32& a, u32& b) {
  asm volatile("v_permlane32_swap_b32 %0, %1" : "+v"(a), "+v"(b));
}

// ---------------- row LayerNorm: fp32 in -> bf16 out, one block per row of 1024 ----------------
__global__ __launch_bounds__(256) void ln_f32(const float* __restrict__ x,
                                              const float* __restrict__ g,
                                              const float* __restrict__ b,
                                              bf16* __restrict__ y) {
  long base = (long)blockIdx.x * 1024;
  int tid = threadIdx.x;
  float v[4];
#pragma unroll
  for (int i = 0; i < 4; i++) v[i] = x[base + tid + i * 256];
  float s1 = v[0] + v[1] + v[2] + v[3];
  float s2 = v[0] * v[0] + v[1] * v[1] + v[2] * v[2] + v[3] * v[3];
#pragma unroll
  for (int off = 32; off; off >>= 1) {
    s1 += __shfl_xor(s1, off);
    s2 += __shfl_xor(s2, off);
  }
  __shared__ float aux[2][4];
  int wave = tid >> 6, lane = tid & 63;
  if (lane == 0) { aux[0][wave] = s1; aux[1][wave] = s2; }
  __syncthreads();
  float S1 = aux[0][0] + aux[0][1] + aux[0][2] + aux[0][3];
  float S2 = aux[1][0] + aux[1][1] + aux[1][2] + aux[1][3];
  float mean = S1 * (1.0f / 1024.0f);
  float var = S2 * (1.0f / 1024.0f) - mean * mean;
  float rs = rsqrtf(var + 1e-5f);
#pragma unroll
  for (int i = 0; i < 4; i++) {
    int c = tid + i * 256;
    y[base + c] = (bf16)(((v[i] - mean) * rs) * g[c] + b[c]);
  }
}

// ---------------- W[K][N] fp32 -> Wt[N][K] bf16 tiled transpose ----------------
__global__ __launch_bounds__(256) void transpose_w(const float* __restrict__ W,
                                                   bf16* __restrict__ Wt,
                                                   int K, int N) {
  __shared__ bf16 tile[64][66];
  int n0 = blockIdx.x * 64, k0 = blockIdx.y * 64;
  int c = threadIdx.x & 63, r4 = threadIdx.x >> 6;
#pragma unroll
  for (int i = 0; i < 16; i++)
    tile[i * 4 + r4][c] = (bf16)W[(long)(k0 + i * 4 + r4) * N + n0 + c];
  __syncthreads();
#pragma unroll
  for (int i = 0; i < 16; i++)
    Wt[(long)(n0 + i * 4 + r4) * K + k0 + c] = tile[c][i * 4 + r4];
}

// ------- extract V^T per (b,h): Vt[bh][d][n] = KV[b*1024+n][1024 + h*64 + d] (bf16) -------
__global__ __launch_bounds__(256) void extract_vt(const bf16* __restrict__ KV,
                                                  bf16* __restrict__ Vt) {
  __shared__ bf16 tile[64][66];
  int bh = blockIdx.z, b = bh >> 4, h = bh & 15;
  const bf16* src = KV + (long)b * 1024 * 2048 + 1024 + h * 64;
  bf16* dst = Vt + (long)bh * 64 * 1024;
  int n0 = blockIdx.x * 64;
  int c = threadIdx.x & 63, r4 = threadIdx.x >> 6;
#pragma unroll
  for (int i = 0; i < 16; i++)
    tile[i * 4 + r4][c] = src[(long)(n0 + i * 4 + r4) * 2048 + c];
  __syncthreads();
#pragma unroll
  for (int i = 0; i < 16; i++)
    dst[(long)(i * 4 + r4) * 1024 + n0 + c] = tile[c][i * 4 + r4];
}

// ---------------- fused flash attention, swapped-QK^T in-register softmax ----------------
__global__ __launch_bounds__(256) void attn_fused(
    const bf16* __restrict__ Q,   // [4096][1024]
    const bf16* __restrict__ KV,  // [4096][2048], K at col h*64
    const bf16* __restrict__ Vt,  // [64 bh][64 d][1024 n]
    bf16* __restrict__ X) {       // [4096][1024]
  __shared__ __align__(16) bf16 Qs[128 * 64];      // 16KB, dead after qf load (epilogue reuse)
  __shared__ __align__(16) bf16 Ks[2][64 * 128];   // 32KB
  __shared__ __align__(16) bf16 Vs[2][64 * 128];   // 32KB
  int tid = threadIdx.x, wave = tid >> 6, lane = tid & 63;
  int l31 = lane & 31, h = lane >> 5;
  int bh = blockIdx.y, b = bh >> 4, hd = bh & 15;
  const bf16* Qb = Q + (long)b * 1048576 + hd * 64;   // ld 1024
  const bf16* Kb = KV + (long)b * 2097152 + hd * 64;  // ld 2048
  const bf16* Vb = Vt + (long)bh * 65536;             // ld 1024
  bf16* Xb = X + (long)b * 1048576 + hd * 64;         // ld 1024
  int q0 = blockIdx.x * 128;

  // per-thread staging coords (chunk-invariant)
  const bf16* gk[4];
  const bf16* gv[4];
  int eoKV[4];
#pragma unroll
  for (int t = 0; t < 4; t++) {
    int eo = (t * 256 + tid) * 8;
    eoKV[t] = eo;
    int r2 = eo >> 7, pp = (eo & 127) >> 3, q = pp ^ (r2 & 15);
    gk[t] = &Kb[(long)(r2 + ((q >> 3) << 6)) * 2048 + ((q & 7) << 3)];
    gv[t] = &Vb[(long)r2 * 1024 + (q << 3)];
  }

  // prologue: stage Q (8-slot xor) + K/V chunk 0
#pragma unroll
  for (int t = 0; t < 4; t++) {
    int eo = (t * 256 + tid) * 8;
    int r = eo >> 6, p = (eo & 63) >> 3;
    int c = (p ^ (r & 7)) << 3;
    GLOAD_LDS16(&Qb[(long)(q0 + r) * 1024 + c], &Qs[eo]);
  }
#pragma unroll
  for (int t = 0; t < 4; t++) GLOAD_LDS16(gk[t], &Ks[0][eoKV[t]]);
#pragma unroll
  for (int t = 0; t < 4; t++) GLOAD_LDS16(gv[t], &Vs[0][eoKV[t]]);
  __syncthreads();

  // Q fragments (B-operand rows q = wave*32+l31), resident for whole kernel
  bf16x8 qf[4];
  {
    int r = wave * 32 + l31;
#pragma unroll
    for (int dw = 0; dw < 4; dw++) {
      int p = (dw * 2 + h) ^ (r & 7);
      qf[dw] = *(const bf16x8*)&Qs[r * 64 + p * 8];
    }
  }

  const float C = 0.18033688011112042f;  // SCALE * log2(e)
  float m_run = -1e30f, l_run = 0.0f;
  f32x16 acc[2] = {};
  int cur = 0;

  for (int kc = 0; kc < 8; kc++) {
    if (kc < 7) {
#pragma unroll
      for (int t = 0; t < 4; t++)
        GLOAD_LDS16(gk[t] + (long)(kc + 1) * 128 * 2048, &Ks[cur ^ 1][eoKV[t]]);
#pragma unroll
      for (int t = 0; t < 4; t++)
        GLOAD_LDS16(gv[t] + (kc + 1) * 128, &Vs[cur ^ 1][eoKV[t]]);
    }
    const bf16* ks = Ks[cur];
    const bf16* vs = Vs[cur];

    // S^T tiles [32 k][32 q], 4 per chunk
    f32x16 s[4] = {};
#pragma unroll
    for (int kt = 0; kt < 4; kt++) {
      int k = kt * 32 + l31;
      int r2 = k & 63, hi = k >> 6;
#pragma unroll
      for (int dw = 0; dw < 4; dw++) {
        int p = (hi * 8 + dw * 2 + h) ^ (r2 & 15);
        bf16x8 kf = *(const bf16x8*)&ks[r2 * 128 + p * 8];
        s[kt] = __builtin_amdgcn_mfma_f32_32x32x16_bf16(kf, qf[dw], s[kt], 0, 0, 0);
      }
    }

    // online softmax: lane owns q = l31; regs hold 64 of 128 k (rest in lane^32)
    float mk[4];
#pragma unroll
    for (int kt = 0; kt < 4; kt++) {
      float m01 = fmaxf(fmaxf(s[kt][0], s[kt][1]), fmaxf(s[kt][2], s[kt][3]));
      float m23 = fmaxf(fmaxf(s[kt][4], s[kt][5]), fmaxf(s[kt][6], s[kt][7]));
      float m45 = fmaxf(fmaxf(s[kt][8], s[kt][9]), fmaxf(s[kt][10], s[kt][11]));
      float m67 = fmaxf(fmaxf(s[kt][12], s[kt][13]), fmaxf(s[kt][14], s[kt][15]));
      mk[kt] = fmaxf(fmaxf(m01, m23), fmaxf(m45, m67));
    }
    float mx = fmaxf(fmaxf(mk[0], mk[1]), fmaxf(mk[2], mk[3]));
    mx = fmaxf(mx, __shfl_xor(mx, 32));
    float m_new = fmaxf(m_run, mx);
    float alpha = exp2f((m_run - m_new) * C);
    m_run = m_new;
    float mc = m_new * C;
    float rk[4];
#pragma unroll
    for (int kt = 0; kt < 4; kt++) {
      float r0 = 0.0f;
#pragma unroll
      for (int r = 0; r < 16; r++) {
        float pv = exp2f(s[kt][r] * C - mc);
        s[kt][r] = pv;
        r0 += pv;
      }
      rk[kt] = r0;
    }
    float rs = (rk[0] + rk[1]) + (rk[2] + rk[3]);
    rs += __shfl_xor(rs, 32);
    l_run = l_run * alpha + rs;
#pragma unroll
    for (int nt = 0; nt < 2; nt++)
#pragma unroll
      for (int r = 0; r < 16; r++) acc[nt][r] *= alpha;

    // PV: per 16-k window, build P B-frag in-register (cvt_pk + 2 permlane swaps)
#pragma unroll
    for (int kw = 0; kw < 8; kw++) {
      int kt = kw >> 1, rb = (kw & 1) * 8;
      u32 wA = pk_bf16(s[kt][rb + 0], s[kt][rb + 1]);
      u32 wB = pk_bf16(s[kt][rb + 2], s[kt][rb + 3]);
      u32 wC = pk_bf16(s[kt][rb + 4], s[kt][rb + 5]);
      u32 wD = pk_bf16(s[kt][rb + 6], s[kt][rb + 7]);
      plane32_swap(wA, wC);
      plane32_swap(wB, wD);
      u32x4 wv = {wA, wB, wC, wD};
      bf16x8 pf = __builtin_bit_cast(bf16x8, wv);
#pragma unroll
      for (int nt = 0; nt < 2; nt++) {
        int r2 = nt * 32 + l31;
        int p = (kw * 2 + h) ^ (r2 & 15);
        bf16x8 vf = *(const bf16x8*)&vs[r2 * 128 + p * 8];
        acc[nt] = __builtin_amdgcn_mfma_f32_32x32x16_bf16(vf, pf, acc[nt], 0, 0, 0);
      }
    }

    if (kc < 7) {
      __syncthreads();
      cur ^= 1;
    }
  }

  // epilogue: O^T -> O via dead Qs region (wave-private rows, no barrier needed).
  float fs = SCALE / l_run;  // second faithful SCALE folded with 1/l
  bf16* Os = Qs;
  int qrow = wave * 32 + l31;
#pragma unroll
  for (int nt = 0; nt < 2; nt++)
#pragma unroll
    for (int g = 0; g < 4; g++) {
      u32 w0 = pk_bf16(acc[nt][g * 4 + 0] * fs, acc[nt][g * 4 + 1] * fs);
      u32 w1 = pk_bf16(acc[nt][g * 4 + 2] * fs, acc[nt][g * 4 + 3] * fs);
      int s8 = nt * 8 + g * 2 + h;
      int phys = s8 ^ (qrow & 15);
      u32x2 wv = {w0, w1};
      *(u32x2*)&Os[qrow * 64 + phys * 4] = wv;
    }
  int rrow = wave * 32 + (lane >> 1);
  int cbase = (lane & 1) * 32;
#pragma unroll
  for (int t2 = 0; t2 < 4; t2++) {
    int s0 = (lane & 1) * 8 + t2 * 2;
    u32x2 a = *(u32x2*)&Os[rrow * 64 + ((s0 ^ (rrow & 15)) * 4)];
    u32x2 bb = *(u32x2*)&Os[rrow * 64 + (((s0 + 1) ^ (rrow & 15)) * 4)];
    u32x4 o4 = {a[0], a[1], bb[0], bb[1]};
    *(u32x4*)&Xb[(long)(q0 + rrow) * 1024 + cbase + t2 * 8] = o4;
  }
}

// ---------------- pipelined C = A @ Bt^T (+epilogue), triple-buffered, counted vmcnt ----------------
// A[M,K] bf16 (lda), Bt[N,K] bf16 (ldb). BK=64. 512 threads = 8 waves (WR x WC).
// LDS: 3 tile-buffers; rows 128B, 16B-slot p -> p^(row&7) (0-conflict proven).
// ONE barrier + ONE counted vmcnt per K-tile:
//   { ds_read all frags(buf b) | issue prefetch t+2 -> buf (b+2)%3 | lgkmcnt(0)
//     | sched_barrier | setprio(1) MFMA setprio(0) | vmcnt(L) | s_barrier }
// Hazards: reads of buf b retire before tile t's barrier (lgkm wait precedes MFMA
// precedes barrier), so staging into buf(t-1) from a faster wave is safe; vmcnt(L)
// retires exactly tile t+1's L loads (t+2's stay in flight; never drains mid-loop).
// EPI: 0 = store bf16; 1 = acc+bias+res (CF32 fp32 C; RBF16 bf16 res); 2 = gelu -> bf16
template <int BM, int BN, int WR, int WC, int EPI, int CF32, int RBF16>
__global__ __launch_bounds__(512) void gemm_p(
    const bf16* __restrict__ A, int lda,
    const bf16* __restrict__ B, int ldb,
    void* __restrict__ Cv, int ldc, int K,
    const float* __restrict__ bias,
    const void* __restrict__ resv, int ldr) {
  constexpr int MT = BM / (16 * WR);
  constexpr int NT = BN / (16 * WC);
  constexpr int L = (BM + BN) / 64;      // gloads/thread/tile
  constexpr int LA = BM / 64;
  constexpr int AE = BM * 64;
  constexpr int BUFE = (BM + BN) * 64;
  __shared__ __align__(16) bf16 lds[3 * BUFE];
  int tid = threadIdx.x;
  int wave = tid >> 6, lane = tid & 63;
  int wm = wave / WC, wn = wave % WC;
  int quad = lane >> 4, l16 = lane & 15;
  int m0 = blockIdx.y * BM, n0 = blockIdx.x * BN;

  // per-thread staging descriptors (compile-time indexed -> registers)
  const bf16* gp[L];
  int lo[L];
#pragma unroll
  for (int i = 0; i < L; i++) {
    if (i < LA) {
      int eo = (i * 512 + tid) * 8;
      int r = eo >> 6, p = (eo & 63) >> 3;
      int c = (p ^ (r & 7)) << 3;
      gp[i] = &A[(long)(m0 + r) * lda + c];
      lo[i] = eo;
    } else {
      int eo = ((i - LA) * 512 + tid) * 8;
      int r = eo >> 6, p = (eo & 63) >> 3;
      int c = (p ^ (r & 7)) << 3;
      gp[i] = &B[(long)(n0 + r) * ldb + c];
      lo[i] = AE + eo;
    }
  }

  int ntk = K >> 6;
  // prologue: stage tiles 0 and 1; wait tile 0 (vmcnt(L) keeps tile 1 in flight)
#pragma unroll
  for (int i = 0; i < L; i++) GLOAD_LDS16(gp[i], &lds[lo[i]]);
#pragma unroll
  for (int i = 0; i < L; i++) gp[i] += 64;
#pragma unroll
  for (int i = 0; i < L; i++) GLOAD_LDS16(gp[i], &lds[BUFE + lo[i]]);
#pragma unroll
  for (int i = 0; i < L; i++) gp[i] += 64;  // gp now at tile 2
  vmcnt_wait<L>();
  asm volatile("" ::: "memory");
  __builtin_amdgcn_s_barrier();

  f32x4 acc[MT][NT] = {};
  int b = 0;
  for (int t = 0; t < ntk; t++) {
    const bf16* Al = &lds[b * BUFE];
    const bf16* Bl = &lds[b * BUFE + AE];
    int b2 = b + 2; if (b2 >= 3) b2 -= 3;
    bool more = (t + 2) < ntk;

    // all fragment reads for this K-tile (2 k-steps of 32)
    bf16x8 af[2][MT], bv[2][NT];
#pragma unroll
    for (int ks = 0; ks < 2; ks++) {
#pragma unroll
      for (int mt = 0; mt < MT; mt++) {
        int row = wm * (BM / WR) + mt * 16 + l16;
        int p = (ks * 4 + quad) ^ (row & 7);
        af[ks][mt] = *(const bf16x8*)&Al[row * 64 + p * 8];
      }
#pragma unroll
      for (int nt = 0; nt < NT; nt++) {
        int row = wn * (BN / WC) + nt * 16 + l16;
        int p = (ks * 4 + quad) ^ (row & 7);
        bv[ks][nt] = *(const bf16x8*)&Bl[row * 64 + p * 8];
      }
    }
    // prefetch tile t+2 into buffer b2
    if (more) {
#pragma unroll
      for (int i = 0; i < L; i++) GLOAD_LDS16(gp[i], &lds[b2 * BUFE + lo[i]]);
    }
    asm volatile("s_waitcnt lgkmcnt(0)" ::: "memory");
    __builtin_amdgcn_sched_barrier(0);
    __builtin_amdgcn_s_setprio(1);
#pragma unroll
    for (int ks = 0; ks < 2; ks++)
#pragma unroll
      for (int mt = 0; mt < MT; mt++)
#pragma unroll
        for (int nt = 0; nt < NT; nt++)
          acc[mt][nt] = __builtin_amdgcn_mfma_f32_16x16x32_bf16(
              af[ks][mt], bv[ks][nt], acc[mt][nt], 0, 0, 0);
    __builtin_amdgcn_s_setprio(0);
    __builtin_amdgcn_sched_barrier(0);
    if (more) {
      vmcnt_wait<L>();        // retire tile t+1's loads; t+2's stay in flight
    } else if (t + 1 < ntk) {
      vmcnt_wait<0>();        // tail: tile t+1 fully resident
    }
    if (t + 1 < ntk) {
      asm volatile("" ::: "memory");
      __builtin_amdgcn_s_barrier();
    }
#pragma unroll
    for (int i = 0; i < L; i++) gp[i] += 64;
    b += 1; if (b == 3) b = 0;
  }

  // epilogue (registers only; no barrier needed)
  int gm = m0 + wm * (BM / WR), gn = n0 + wn * (BN / WC);
#pragma unroll
  for (int nt = 0; nt < NT; nt++) {
    int col = gn + nt * 16 + l16;
    float bvb = (EPI != 0) ? bias[col] : 0.0f;
#pragma unroll
    for (int mt = 0; mt < MT; mt++) {
#pragma unroll
      for (int r = 0; r < 4; r++) {
        int row = gm + mt * 16 + quad * 4 + r;
        float v = acc[mt][nt][r] + bvb;
        if (EPI == 2) {
          v = 0.5f * v * (1.0f + erff(v * 0.70710678118654752f));
        } else if (EPI == 1) {
          float rv = RBF16 ? (float)((const bf16*)resv)[(long)row * ldr + col]
                           : ((const float*)resv)[(long)row * ldr + col];
          v += rv;
        }
        if (CF32)
          ((float*)Cv)[(long)row * ldc + col] = v;
        else
          ((bf16*)Cv)[(long)row * ldc + col] = (bf16)v;
      }
    }
  }
}

extern "C" void kernel_launch(void* const* d_in, const int* in_sizes, int n_in,
                              void* d_out, int out_size, void* d_ws, size_t ws_size,
                              hipStream_t stream) {
  const float* src_q  = (const float*)d_in[0];
  const float* src_kv = (const float*)d_in[1];
  const float* gq     = (const float*)d_in[2];
  const float* bq     = (const float*)d_in[3];
  const float* gkv    = (const float*)d_in[4];
  const float* bkv    = (const float*)d_in[5];
  const float* Wq     = (const float*)d_in[6];
  const float* Wkv    = (const float*)d_in[7];
  const float* Wproj  = (const float*)d_in[8];
  const float* bproj  = (const float*)d_in[9];
  const float* gn     = (const float*)d_in[10];
  const float* bn     = (const float*)d_in[11];
  const float* W1     = (const float*)d_in[12];
  const float* b1     = (const float*)d_in[13];
  const float* W2     = (const float*)d_in[14];
  const float* b2     = (const float*)d_in[15];
  float* out = (float*)d_out;

  char* ws = (char*)d_ws;
  const long MB = 1024 * 1024;
  bf16* Wq_t    = (bf16*)(ws + 0 * MB);    // [1024][1024]  2MB   (whole run)
  bf16* Wkv_t   = (bf16*)(ws + 2 * MB);    // [2048][1024]  4MB
  bf16* Wproj_t = (bf16*)(ws + 6 * MB);    // [1024][1024]  2MB
  bf16* W1_t    = (bf16*)(ws + 8 * MB);    // [4096][1024]  8MB
  bf16* W2_t    = (bf16*)(ws + 16 * MB);   // [1024][4096]  8MB  (ld = 4096!)
  bf16* qn      = (bf16*)(ws + 24 * MB);   // [4096][1024]  8MB   dead after Q GEMM
  bf16* kvn     = (bf16*)(ws + 32 * MB);   // [4096][1024]  8MB   dead after KV GEMM
  bf16* Qm      = (bf16*)(ws + 40 * MB);   // [4096][1024]  8MB   dead after attn
  bf16* KVm     = (bf16*)(ws + 48 * MB);   // [4096][2048] 16MB   dead after attn
  bf16* Vt      = (bf16*)(ws + 64 * MB);   // [64][64][1024] 8MB  dead after attn
  bf16* xbuf    = (bf16*)(ws + 24 * MB);   // [4096][1024]  8MB   (reuses qn)
  float* tbuf   = (float*)(ws + 48 * MB);  // [4096][1024] 16MB fp32 (reuses KVm)
  bf16* sbuf    = (bf16*)(ws + 64 * MB);   // [4096][1024]  8MB   (reuses Vt)
  bf16* hbuf    = (bf16*)(ws + 72 * MB);   // [4096][4096] 32MB

  // weight transposes (fp32 -> bf16)
  transpose_w<<<dim3(16, 16), 256, 0, stream>>>(Wq, Wq_t, 1024, 1024);
  transpose_w<<<dim3(32, 16), 256, 0, stream>>>(Wkv, Wkv_t, 1024, 2048);
  transpose_w<<<dim3(16, 16), 256, 0, stream>>>(Wproj, Wproj_t, 1024, 1024);
  transpose_w<<<dim3(64, 16), 256, 0, stream>>>(W1, W1_t, 1024, 4096);
  transpose_w<<<dim3(16, 64), 256, 0, stream>>>(W2, W2_t, 4096, 1024);

  // LayerNorms (fp32 -> bf16)
  ln_f32<<<4096, 256, 0, stream>>>(src_q, gq, bq, qn);
  ln_f32<<<4096, 256, 0, stream>>>(src_kv, gkv, bkv, kvn);

  // Q = qn @ Wq   (M=4096, N=1024, K=1024): 128x128, 256 blocks
  gemm_p<128, 128, 2, 4, 0, 0, 0><<<dim3(8, 32), 512, 0, stream>>>(
      qn, 1024, Wq_t, 1024, Qm, 1024, 1024, nullptr, nullptr, 0);
  // KV = kvn @ Wkv  (M=4096, N=2048, K=1024): 256x128, 256 blocks
  gemm_p<256, 128, 4, 2, 0, 0, 0><<<dim3(16, 16), 512, 0, stream>>>(
      kvn, 1024, Wkv_t, 1024, KVm, 2048, 1024, nullptr, nullptr, 0);
  extract_vt<<<dim3(16, 1, 64), 256, 0, stream>>>(KVm, Vt);

  // fused flash attention: 8 q-tiles x 64 bh, 512 blocks
  attn_fused<<<dim3(8, 64), 256, 0, stream>>>(Qm, KVm, Vt, xbuf);

  // tbuf = src_q + x @ Wproj + bproj   (fp32 out): 128x128, 256 blocks
  gemm_p<128, 128, 2, 4, 1, 1, 0><<<dim3(8, 32), 512, 0, stream>>>(
      xbuf, 1024, Wproj_t, 1024, tbuf, 1024, 1024, bproj, src_q, 1024);
  // sbuf = LN(tbuf)  (bf16 out)
  ln_f32<<<4096, 256, 0, stream>>>(tbuf, gn, bn, sbuf);
  // hbuf = gelu(sbuf @ W1 + b1)  (bf16 out, N=4096): 256x128, 512 blocks
  gemm_p<256, 128, 4, 2, 2, 0, 0><<<dim3(32, 16), 512, 0, stream>>>(
      sbuf, 1024, W1_t, 1024, hbuf, 4096, 1024, b1, nullptr, 0);
  // out = sbuf + hbuf @ W2 + b2  (fp32 out, K=4096): 128x128, 256 blocks
  gemm_p<128, 128, 2, 4, 1, 1, 1><<<dim3(8, 32), 512, 0, stream>>>(
      hbuf, 4096, W2_t, 4096, out, 1024, 4096, b2, sbuf, 1024);
}

// Round 4
// 355.537 us; speedup vs baseline: 1.2265x; 1.0361x over previous
//
#include <hip/hip_runtime.h>
#include <hip/hip_bf16.h>
#include <math.h>

typedef __bf16 bf16;
typedef __bf16 bf16x2 __attribute__((ext_vector_type(2)));
typedef __bf16 bf16x8 __attribute__((ext_vector_type(8)));
typedef float f32x4 __attribute__((ext_vector_type(4)));
typedef float f32x16 __attribute__((ext_vector_type(16)));
typedef unsigned int u32;
typedef unsigned int u32x2 __attribute__((ext_vector_type(2)));
typedef unsigned int u32x4 __attribute__((ext_vector_type(4)));

#define SCALE 0.125f

// async global->LDS, 16B per lane. LDS dest must be wave-uniform base + lane*16.
#define GLOAD_LDS16(gptr, lptr)                                      \
  __builtin_amdgcn_global_load_lds(                                  \
      (const __attribute__((address_space(1))) void*)(gptr),         \
      (__attribute__((address_space(3))) void*)(lptr), 16, 0, 0)

template <int N>
__device__ __forceinline__ void vmcnt_wait() {
  if constexpr (N == 0) asm volatile("s_waitcnt vmcnt(0)" ::: "memory");
  else if constexpr (N == 4) asm volatile("s_waitcnt vmcnt(4)" ::: "memory");
  else if constexpr (N == 6) asm volatile("s_waitcnt vmcnt(6)" ::: "memory");
  else static_assert(N == 0 || N == 4 || N == 6, "unsupported vmcnt");
}

// XCD-chunked bijective block swizzle (T1). HW dispatches flat id w round-robin
// across 8 XCDs (xcd = w%8). Remap so each XCD owns a CONTIGUOUS chunk of an
// (8-wide-x, y)-major enumeration -> per-XCD 8xH 2D tile chunk -> shared A/B
// panels (or shared KV) stay L2-resident. Bijective for gx%8==0, nwg%8==0.
__device__ __forceinline__ void xcd_swz(int gx, int gy, int& x, int& y) {
  int w = blockIdx.x + gx * blockIdx.y;
  int nwg = gx * gy;
  int wp = (w & 7) * (nwg >> 3) + (w >> 3);
  int xi = wp & 7;
  int t = wp >> 3;
  y = t % gy;
  x = (t / gy) * 8 + xi;
}

// pack two f32 -> one u32 of 2 bf16 (RNE); compiler emits v_cvt_pk_bf16_f32
__device__ __forceinline__ u32 pk_bf16(float lo, float hi) {
  bf16x2 t;
  t[0] = (bf16)lo;
  t[1] = (bf16)hi;
  return __builtin_bit_cast(u32, t);
}

// v_permlane32_swap_b32: a.hi <-> b.lo
__device__ __forceinline__ void plane32_swap(u32& a, u32& b) {
  asm volatile("v_permlane32_swap_b32 %0, %1" : "+v"(a), "+v"(b));
}

// ---------------- row LayerNorm: fp32 in -> bf16 out, one block per row of 1024 ----------------
__global__ __launch_bounds__(256) void ln_f32(const float* __restrict__ x,
                                              const float* __restrict__ g,
                                              const float* __restrict__ b,
                                              bf16* __restrict__ y) {
  long base = (long)blockIdx.x * 1024;
  int tid = threadIdx.x;
  float v[4];
#pragma unroll
  for (int i = 0; i < 4; i++) v[i] = x[base + tid + i * 256];
  float s1 = v[0] + v[1] + v[2] + v[3];
  float s2 = v[0] * v[0] + v[1] * v[1] + v[2] * v[2] + v[3] * v[3];
#pragma unroll
  for (int off = 32; off; off >>= 1) {
    s1 += __shfl_xor(s1, off);
    s2 += __shfl_xor(s2, off);
  }
  __shared__ float aux[2][4];
  int wave = tid >> 6, lane = tid & 63;
  if (lane == 0) { aux[0][wave] = s1; aux[1][wave] = s2; }
  __syncthreads();
  float S1 = aux[0][0] + aux[0][1] + aux[0][2] + aux[0][3];
  float S2 = aux[1][0] + aux[1][1] + aux[1][2] + aux[1][3];
  float mean = S1 * (1.0f / 1024.0f);
  float var = S2 * (1.0f / 1024.0f) - mean * mean;
  float rs = rsqrtf(var + 1e-5f);
#pragma unroll
  for (int i = 0; i < 4; i++) {
    int c = tid + i * 256;
    y[base + c] = (bf16)(((v[i] - mean) * rs) * g[c] + b[c]);
  }
}

// ---------------- W[K][N] fp32 -> Wt[N][K] bf16 tiled transpose ----------------
__global__ __launch_bounds__(256) void transpose_w(const float* __restrict__ W,
                                                   bf16* __restrict__ Wt,
                                                   int K, int N) {
  __shared__ bf16 tile[64][66];
  int n0 = blockIdx.x * 64, k0 = blockIdx.y * 64;
  int c = threadIdx.x & 63, r4 = threadIdx.x >> 6;
#pragma unroll
  for (int i = 0; i < 16; i++)
    tile[i * 4 + r4][c] = (bf16)W[(long)(k0 + i * 4 + r4) * N + n0 + c];
  __syncthreads();
#pragma unroll
  for (int i = 0; i < 16; i++)
    Wt[(long)(n0 + i * 4 + r4) * K + k0 + c] = tile[c][i * 4 + r4];
}

// ------- extract V^T per (b,h): Vt[bh][d][n] = KV[b*1024+n][1024 + h*64 + d] (bf16) -------
__global__ __launch_bounds__(256) void extract_vt(const bf16* __restrict__ KV,
                                                  bf16* __restrict__ Vt) {
  __shared__ bf16 tile[64][66];
  int bh = blockIdx.z, b = bh >> 4, h = bh & 15;
  const bf16* src = KV + (long)b * 1024 * 2048 + 1024 + h * 64;
  bf16* dst = Vt + (long)bh * 64 * 1024;
  int n0 = blockIdx.x * 64;
  int c = threadIdx.x & 63, r4 = threadIdx.x >> 6;
#pragma unroll
  for (int i = 0; i < 16; i++)
    tile[i * 4 + r4][c] = src[(long)(n0 + i * 4 + r4) * 2048 + c];
  __syncthreads();
#pragma unroll
  for (int i = 0; i < 16; i++)
    dst[(long)(i * 4 + r4) * 1024 + n0 + c] = tile[c][i * 4 + r4];
}

// ---------------- fused flash attention, swapped-QK^T in-register softmax ----------------
// XCD-swizzled grid: 8 q-tiles of the same (b,h) co-locate on one XCD -> KV L2-resident.
__global__ __launch_bounds__(256) void attn_fused(
    const bf16* __restrict__ Q,   // [4096][1024]
    const bf16* __restrict__ KV,  // [4096][2048], K at col h*64
    const bf16* __restrict__ Vt,  // [64 bh][64 d][1024 n]
    bf16* __restrict__ X) {       // [4096][1024]
  __shared__ __align__(16) bf16 Qs[128 * 64];      // 16KB, dead after qf load (epilogue reuse)
  __shared__ __align__(16) bf16 Ks[2][64 * 128];   // 32KB
  __shared__ __align__(16) bf16 Vs[2][64 * 128];   // 32KB
  int tid = threadIdx.x, wave = tid >> 6, lane = tid & 63;
  int l31 = lane & 31, h = lane >> 5;
  int bqx, bhy;
  xcd_swz(8, 64, bqx, bhy);
  int bh = bhy, b = bh >> 4, hd = bh & 15;
  const bf16* Qb = Q + (long)b * 1048576 + hd * 64;   // ld 1024
  const bf16* Kb = KV + (long)b * 2097152 + hd * 64;  // ld 2048
  const bf16* Vb = Vt + (long)bh * 65536;             // ld 1024
  bf16* Xb = X + (long)b * 1048576 + hd * 64;         // ld 1024
  int q0 = bqx * 128;

  // per-thread staging coords (chunk-invariant)
  const bf16* gk[4];
  const bf16* gv[4];
  int eoKV[4];
#pragma unroll
  for (int t = 0; t < 4; t++) {
    int eo = (t * 256 + tid) * 8;
    eoKV[t] = eo;
    int r2 = eo >> 7, pp = (eo & 127) >> 3, q = pp ^ (r2 & 15);
    gk[t] = &Kb[(long)(r2 + ((q >> 3) << 6)) * 2048 + ((q & 7) << 3)];
    gv[t] = &Vb[(long)r2 * 1024 + (q << 3)];
  }

  // prologue: stage Q (8-slot xor) + K/V chunk 0
#pragma unroll
  for (int t = 0; t < 4; t++) {
    int eo = (t * 256 + tid) * 8;
    int r = eo >> 6, p = (eo & 63) >> 3;
    int c = (p ^ (r & 7)) << 3;
    GLOAD_LDS16(&Qb[(long)(q0 + r) * 1024 + c], &Qs[eo]);
  }
#pragma unroll
  for (int t = 0; t < 4; t++) GLOAD_LDS16(gk[t], &Ks[0][eoKV[t]]);
#pragma unroll
  for (int t = 0; t < 4; t++) GLOAD_LDS16(gv[t], &Vs[0][eoKV[t]]);
  __syncthreads();

  // Q fragments (B-operand rows q = wave*32+l31), resident for whole kernel
  bf16x8 qf[4];
  {
    int r = wave * 32 + l31;
#pragma unroll
    for (int dw = 0; dw < 4; dw++) {
      int p = (dw * 2 + h) ^ (r & 7);
      qf[dw] = *(const bf16x8*)&Qs[r * 64 + p * 8];
    }
  }

  const float C = 0.18033688011112042f;  // SCALE * log2(e)
  float m_run = -1e30f, l_run = 0.0f;
  f32x16 acc[2] = {};
  int cur = 0;

  for (int kc = 0; kc < 8; kc++) {
    if (kc < 7) {
#pragma unroll
      for (int t = 0; t < 4; t++)
        GLOAD_LDS16(gk[t] + (long)(kc + 1) * 128 * 2048, &Ks[cur ^ 1][eoKV[t]]);
#pragma unroll
      for (int t = 0; t < 4; t++)
        GLOAD_LDS16(gv[t] + (kc + 1) * 128, &Vs[cur ^ 1][eoKV[t]]);
    }
    const bf16* ks = Ks[cur];
    const bf16* vs = Vs[cur];

    // S^T tiles [32 k][32 q], 4 per chunk
    f32x16 s[4] = {};
#pragma unroll
    for (int kt = 0; kt < 4; kt++) {
      int k = kt * 32 + l31;
      int r2 = k & 63, hi = k >> 6;
#pragma unroll
      for (int dw = 0; dw < 4; dw++) {
        int p = (hi * 8 + dw * 2 + h) ^ (r2 & 15);
        bf16x8 kf = *(const bf16x8*)&ks[r2 * 128 + p * 8];
        s[kt] = __builtin_amdgcn_mfma_f32_32x32x16_bf16(kf, qf[dw], s[kt], 0, 0, 0);
      }
    }

    // online softmax: lane owns q = l31; regs hold 64 of 128 k (rest in lane^32)
    float mk[4];
#pragma unroll
    for (int kt = 0; kt < 4; kt++) {
      float m01 = fmaxf(fmaxf(s[kt][0], s[kt][1]), fmaxf(s[kt][2], s[kt][3]));
      float m23 = fmaxf(fmaxf(s[kt][4], s[kt][5]), fmaxf(s[kt][6], s[kt][7]));
      float m45 = fmaxf(fmaxf(s[kt][8], s[kt][9]), fmaxf(s[kt][10], s[kt][11]));
      float m67 = fmaxf(fmaxf(s[kt][12], s[kt][13]), fmaxf(s[kt][14], s[kt][15]));
      mk[kt] = fmaxf(fmaxf(m01, m23), fmaxf(m45, m67));
    }
    float mx = fmaxf(fmaxf(mk[0], mk[1]), fmaxf(mk[2], mk[3]));
    mx = fmaxf(mx, __shfl_xor(mx, 32));
    float m_new = fmaxf(m_run, mx);
    float alpha = exp2f((m_run - m_new) * C);
    m_run = m_new;
    float mc = m_new * C;
    float rk[4];
#pragma unroll
    for (int kt = 0; kt < 4; kt++) {
      float r0 = 0.0f;
#pragma unroll
      for (int r = 0; r < 16; r++) {
        float pv = exp2f(s[kt][r] * C - mc);
        s[kt][r] = pv;
        r0 += pv;
      }
      rk[kt] = r0;
    }
    float rs = (rk[0] + rk[1]) + (rk[2] + rk[3]);
    rs += __shfl_xor(rs, 32);
    l_run = l_run * alpha + rs;
#pragma unroll
    for (int nt = 0; nt < 2; nt++)
#pragma unroll
      for (int r = 0; r < 16; r++) acc[nt][r] *= alpha;

    // PV: per 16-k window, build P B-frag in-register (cvt_pk + 2 permlane swaps)
#pragma unroll
    for (int kw = 0; kw < 8; kw++) {
      int kt = kw >> 1, rb = (kw & 1) * 8;
      u32 wA = pk_bf16(s[kt][rb + 0], s[kt][rb + 1]);
      u32 wB = pk_bf16(s[kt][rb + 2], s[kt][rb + 3]);
      u32 wC = pk_bf16(s[kt][rb + 4], s[kt][rb + 5]);
      u32 wD = pk_bf16(s[kt][rb + 6], s[kt][rb + 7]);
      plane32_swap(wA, wC);
      plane32_swap(wB, wD);
      u32x4 wv = {wA, wB, wC, wD};
      bf16x8 pf = __builtin_bit_cast(bf16x8, wv);
#pragma unroll
      for (int nt = 0; nt < 2; nt++) {
        int r2 = nt * 32 + l31;
        int p = (kw * 2 + h) ^ (r2 & 15);
        bf16x8 vf = *(const bf16x8*)&vs[r2 * 128 + p * 8];
        acc[nt] = __builtin_amdgcn_mfma_f32_32x32x16_bf16(vf, pf, acc[nt], 0, 0, 0);
      }
    }

    if (kc < 7) {
      __syncthreads();
      cur ^= 1;
    }
  }

  // epilogue: O^T -> O via dead Qs region (wave-private rows, no barrier needed).
  float fs = SCALE / l_run;  // second faithful SCALE folded with 1/l
  bf16* Os = Qs;
  int qrow = wave * 32 + l31;
#pragma unroll
  for (int nt = 0; nt < 2; nt++)
#pragma unroll
    for (int g = 0; g < 4; g++) {
      u32 w0 = pk_bf16(acc[nt][g * 4 + 0] * fs, acc[nt][g * 4 + 1] * fs);
      u32 w1 = pk_bf16(acc[nt][g * 4 + 2] * fs, acc[nt][g * 4 + 3] * fs);
      int s8 = nt * 8 + g * 2 + h;
      int phys = s8 ^ (qrow & 15);
      u32x2 wv = {w0, w1};
      *(u32x2*)&Os[qrow * 64 + phys * 4] = wv;
    }
  int rrow = wave * 32 + (lane >> 1);
  int cbase = (lane & 1) * 32;
#pragma unroll
  for (int t2 = 0; t2 < 4; t2++) {
    int s0 = (lane & 1) * 8 + t2 * 2;
    u32x2 a = *(u32x2*)&Os[rrow * 64 + ((s0 ^ (rrow & 15)) * 4)];
    u32x2 bb = *(u32x2*)&Os[rrow * 64 + (((s0 + 1) ^ (rrow & 15)) * 4)];
    u32x4 o4 = {a[0], a[1], bb[0], bb[1]};
    *(u32x4*)&Xb[(long)(q0 + rrow) * 1024 + cbase + t2 * 8] = o4;
  }
}

// ---------------- pipelined C = A @ Bt^T (+epilogue), triple-buffered, counted vmcnt ----------------
// A[M,K] bf16 (lda), Bt[N,K] bf16 (ldb). BK=64. 512 threads = 8 waves (WR x WC).
// LDS: 3 tile-buffers; rows 128B, 16B-slot p -> p^(row&7) (0-conflict proven).
// ONE barrier + ONE counted vmcnt per K-tile. XCD-chunked block swizzle for L2 reuse.
// EPI: 0 = store bf16; 1 = acc+bias+res (CF32 fp32 C; RBF16 bf16 res); 2 = gelu -> bf16
template <int BM, int BN, int WR, int WC, int EPI, int CF32, int RBF16>
__global__ __launch_bounds__(512) void gemm_p(
    const bf16* __restrict__ A, int lda,
    const bf16* __restrict__ B, int ldb,
    void* __restrict__ Cv, int ldc, int K,
    const float* __restrict__ bias,
    const void* __restrict__ resv, int ldr) {
  constexpr int MT = BM / (16 * WR);
  constexpr int NT = BN / (16 * WC);
  constexpr int L = (BM + BN) / 64;      // gloads/thread/tile
  constexpr int LA = BM / 64;
  constexpr int AE = BM * 64;
  constexpr int BUFE = (BM + BN) * 64;
  __shared__ __align__(16) bf16 lds[3 * BUFE];
  int tid = threadIdx.x;
  int wave = tid >> 6, lane = tid & 63;
  int wm = wave / WC, wn = wave % WC;
  int quad = lane >> 4, l16 = lane & 15;
  int bx, by;
  xcd_swz(gridDim.x, gridDim.y, bx, by);
  int m0 = by * BM, n0 = bx * BN;

  // per-thread staging descriptors (compile-time indexed -> registers)
  const bf16* gp[L];
  int lo[L];
#pragma unroll
  for (int i = 0; i < L; i++) {
    if (i < LA) {
      int eo = (i * 512 + tid) * 8;
      int r = eo >> 6, p = (eo & 63) >> 3;
      int c = (p ^ (r & 7)) << 3;
      gp[i] = &A[(long)(m0 + r) * lda + c];
      lo[i] = eo;
    } else {
      int eo = ((i - LA) * 512 + tid) * 8;
      int r = eo >> 6, p = (eo & 63) >> 3;
      int c = (p ^ (r & 7)) << 3;
      gp[i] = &B[(long)(n0 + r) * ldb + c];
      lo[i] = AE + eo;
    }
  }

  int ntk = K >> 6;
  // prologue: stage tiles 0 and 1; wait tile 0 (vmcnt(L) keeps tile 1 in flight)
#pragma unroll
  for (int i = 0; i < L; i++) GLOAD_LDS16(gp[i], &lds[lo[i]]);
#pragma unroll
  for (int i = 0; i < L; i++) gp[i] += 64;
#pragma unroll
  for (int i = 0; i < L; i++) GLOAD_LDS16(gp[i], &lds[BUFE + lo[i]]);
#pragma unroll
  for (int i = 0; i < L; i++) gp[i] += 64;  // gp now at tile 2
  vmcnt_wait<L>();
  asm volatile("" ::: "memory");
  __builtin_amdgcn_s_barrier();

  f32x4 acc[MT][NT] = {};
  int b = 0;
  for (int t = 0; t < ntk; t++) {
    const bf16* Al = &lds[b * BUFE];
    const bf16* Bl = &lds[b * BUFE + AE];
    int b2 = b + 2; if (b2 >= 3) b2 -= 3;
    bool more = (t + 2) < ntk;

    // all fragment reads for this K-tile (2 k-steps of 32)
    bf16x8 af[2][MT], bv[2][NT];
#pragma unroll
    for (int ks = 0; ks < 2; ks++) {
#pragma unroll
      for (int mt = 0; mt < MT; mt++) {
        int row = wm * (BM / WR) + mt * 16 + l16;
        int p = (ks * 4 + quad) ^ (row & 7);
        af[ks][mt] = *(const bf16x8*)&Al[row * 64 + p * 8];
      }
#pragma unroll
      for (int nt = 0; nt < NT; nt++) {
        int row = wn * (BN / WC) + nt * 16 + l16;
        int p = (ks * 4 + quad) ^ (row & 7);
        bv[ks][nt] = *(const bf16x8*)&Bl[row * 64 + p * 8];
      }
    }
    // prefetch tile t+2 into buffer b2
    if (more) {
#pragma unroll
      for (int i = 0; i < L; i++) GLOAD_LDS16(gp[i], &lds[b2 * BUFE + lo[i]]);
    }
    asm volatile("s_waitcnt lgkmcnt(0)" ::: "memory");
    __builtin_amdgcn_sched_barrier(0);
    __builtin_amdgcn_s_setprio(1);
#pragma unroll
    for (int ks = 0; ks < 2; ks++)
#pragma unroll
      for (int mt = 0; mt < MT; mt++)
#pragma unroll
        for (int nt = 0; nt < NT; nt++)
          acc[mt][nt] = __builtin_amdgcn_mfma_f32_16x16x32_bf16(
              af[ks][mt], bv[ks][nt], acc[mt][nt], 0, 0, 0);
    __builtin_amdgcn_s_setprio(0);
    __builtin_amdgcn_sched_barrier(0);
    if (more) {
      vmcnt_wait<L>();        // retire tile t+1's loads; t+2's stay in flight
    } else if (t + 1 < ntk) {
      vmcnt_wait<0>();        // tail: tile t+1 fully resident
    }
    if (t + 1 < ntk) {
      asm volatile("" ::: "memory");
      __builtin_amdgcn_s_barrier();
    }
#pragma unroll
    for (int i = 0; i < L; i++) gp[i] += 64;
    b += 1; if (b == 3) b = 0;
  }

  // epilogue (registers only; no barrier needed)
  int gm = m0 + wm * (BM / WR), gn = n0 + wn * (BN / WC);
#pragma unroll
  for (int nt = 0; nt < NT; nt++) {
    int col = gn + nt * 16 + l16;
    float bvb = (EPI != 0) ? bias[col] : 0.0f;
#pragma unroll
    for (int mt = 0; mt < MT; mt++) {
#pragma unroll
      for (int r = 0; r < 4; r++) {
        int row = gm + mt * 16 + quad * 4 + r;
        float v = acc[mt][nt][r] + bvb;
        if (EPI == 2) {
          v = 0.5f * v * (1.0f + erff(v * 0.70710678118654752f));
        } else if (EPI == 1) {
          float rv = RBF16 ? (float)((const bf16*)resv)[(long)row * ldr + col]
                           : ((const float*)resv)[(long)row * ldr + col];
          v += rv;
        }
        if (CF32)
          ((float*)Cv)[(long)row * ldc + col] = v;
        else
          ((bf16*)Cv)[(long)row * ldc + col] = (bf16)v;
      }
    }
  }
}

extern "C" void kernel_launch(void* const* d_in, const int* in_sizes, int n_in,
                              void* d_out, int out_size, void* d_ws, size_t ws_size,
                              hipStream_t stream) {
  const float* src_q  = (const float*)d_in[0];
  const float* src_kv = (const float*)d_in[1];
  const float* gq     = (const float*)d_in[2];
  const float* bq     = (const float*)d_in[3];
  const float* gkv    = (const float*)d_in[4];
  const float* bkv    = (const float*)d_in[5];
  const float* Wq     = (const float*)d_in[6];
  const float* Wkv    = (const float*)d_in[7];
  const float* Wproj  = (const float*)d_in[8];
  const float* bproj  = (const float*)d_in[9];
  const float* gn     = (const float*)d_in[10];
  const float* bn     = (const float*)d_in[11];
  const float* W1     = (const float*)d_in[12];
  const float* b1     = (const float*)d_in[13];
  const float* W2     = (const float*)d_in[14];
  const float* b2     = (const float*)d_in[15];
  float* out = (float*)d_out;

  char* ws = (char*)d_ws;
  const long MB = 1024 * 1024;
  bf16* Wq_t    = (bf16*)(ws + 0 * MB);    // [1024][1024]  2MB   (whole run)
  bf16* Wkv_t   = (bf16*)(ws + 2 * MB);    // [2048][1024]  4MB
  bf16* Wproj_t = (bf16*)(ws + 6 * MB);    // [1024][1024]  2MB
  bf16* W1_t    = (bf16*)(ws + 8 * MB);    // [4096][1024]  8MB
  bf16* W2_t    = (bf16*)(ws + 16 * MB);   // [1024][4096]  8MB  (ld = 4096!)
  bf16* qn      = (bf16*)(ws + 24 * MB);   // [4096][1024]  8MB   dead after Q GEMM
  bf16* kvn     = (bf16*)(ws + 32 * MB);   // [4096][1024]  8MB   dead after KV GEMM
  bf16* Qm      = (bf16*)(ws + 40 * MB);   // [4096][1024]  8MB   dead after attn
  bf16* KVm     = (bf16*)(ws + 48 * MB);   // [4096][2048] 16MB   dead after attn
  bf16* Vt      = (bf16*)(ws + 64 * MB);   // [64][64][1024] 8MB  dead after attn
  bf16* xbuf    = (bf16*)(ws + 24 * MB);   // [4096][1024]  8MB   (reuses qn)
  float* tbuf   = (float*)(ws + 48 * MB);  // [4096][1024] 16MB fp32 (reuses KVm)
  bf16* sbuf    = (bf16*)(ws + 64 * MB);   // [4096][1024]  8MB   (reuses Vt)
  bf16* hbuf    = (bf16*)(ws + 72 * MB);   // [4096][4096] 32MB

  // weight transposes (fp32 -> bf16)
  transpose_w<<<dim3(16, 16), 256, 0, stream>>>(Wq, Wq_t, 1024, 1024);
  transpose_w<<<dim3(32, 16), 256, 0, stream>>>(Wkv, Wkv_t, 1024, 2048);
  transpose_w<<<dim3(16, 16), 256, 0, stream>>>(Wproj, Wproj_t, 1024, 1024);
  transpose_w<<<dim3(64, 16), 256, 0, stream>>>(W1, W1_t, 1024, 4096);
  transpose_w<<<dim3(16, 64), 256, 0, stream>>>(W2, W2_t, 4096, 1024);

  // LayerNorms (fp32 -> bf16)
  ln_f32<<<4096, 256, 0, stream>>>(src_q, gq, bq, qn);
  ln_f32<<<4096, 256, 0, stream>>>(src_kv, gkv, bkv, kvn);

  // Q = qn @ Wq   (M=4096, N=1024, K=1024): 128x128, 256 blocks
  gemm_p<128, 128, 2, 4, 0, 0, 0><<<dim3(8, 32), 512, 0, stream>>>(
      qn, 1024, Wq_t, 1024, Qm, 1024, 1024, nullptr, nullptr, 0);
  // KV = kvn @ Wkv  (M=4096, N=2048, K=1024): 256x128, 256 blocks
  gemm_p<256, 128, 4, 2, 0, 0, 0><<<dim3(16, 16), 512, 0, stream>>>(
      kvn, 1024, Wkv_t, 1024, KVm, 2048, 1024, nullptr, nullptr, 0);
  extract_vt<<<dim3(16, 1, 64), 256, 0, stream>>>(KVm, Vt);

  // fused flash attention: 8 q-tiles x 64 bh, 512 blocks
  attn_fused<<<dim3(8, 64), 256, 0, stream>>>(Qm, KVm, Vt, xbuf);

  // tbuf = src_q + x @ Wproj + bproj   (fp32 out): 128x128, 256 blocks
  gemm_p<128, 128, 2, 4, 1, 1, 0><<<dim3(8, 32), 512, 0, stream>>>(
      xbuf, 1024, Wproj_t, 1024, tbuf, 1024, 1024, bproj, src_q, 1024);
  // sbuf = LN(tbuf)  (bf16 out)
  ln_f32<<<4096, 256, 0, stream>>>(tbuf, gn, bn, sbuf);
  // hbuf = gelu(sbuf @ W1 + b1)  (bf16 out, N=4096): 256x128, 512 blocks
  gemm_p<256, 128, 4, 2, 2, 0, 0><<<dim3(32, 16), 512, 0, stream>>>(
      sbuf, 1024, W1_t, 1024, hbuf, 4096, 1024, b1, nullptr, 0);
  // out = sbuf + hbuf @ W2 + b2  (fp32 out, K=4096): 128x128, 256 blocks
  gemm_p<128, 128, 2, 4, 1, 1, 1><<<dim3(8, 32), 512, 0, stream>>>(
      hbuf, 4096, W2_t, 4096, out, 1024, 4096, b2, sbuf, 1024);
}